// Round 7
// baseline (379.246 us; speedup 1.0000x reference)
//
#include <hip/hip_runtime.h>
#include <hip/hip_bf16.h>
#include <hip/hip_cooperative_groups.h>
#include <cmath>

namespace cg = cooperative_groups;

#define B_SZ 4
#define N_SEQ 2048
#define DIM 512
#define NH 8
#define DH 64
#define QKV_N 1536
#define ROWS (B_SZ * N_SEQ)   // 8192

typedef __bf16 bf16x8 __attribute__((ext_vector_type(8)));
typedef __bf16 bf16x4 __attribute__((ext_vector_type(4)));
typedef float  f32x4  __attribute__((ext_vector_type(4)));

#define GLOAD_LDS16(gp, lp)                                                     \
    __builtin_amdgcn_global_load_lds(                                           \
        (const __attribute__((address_space(1))) void*)(gp),                    \
        (__attribute__((address_space(3))) void*)(lp), 16, 0, 0)

#define MFMA_BF16 __builtin_amdgcn_mfma_f32_16x16x32_bf16

// raw workgroup barrier WITHOUT the compiler's implicit vmcnt(0)/lgkmcnt(0) drain
#define SBAR() asm volatile("s_barrier" ::: "memory")

// ---------------- rms-norm + gamma + bf16 cast body (4 rows / 256 threads) ----
__device__ __forceinline__ void rms_body(const float* __restrict__ x,
                                         const float* __restrict__ gamma,
                                         __bf16* __restrict__ A, int vb, int t) {
    const int row  = vb * 4 + (t >> 6);
    const int lane = t & 63;
    const float4* xr = (const float4*)(x + (size_t)row * DIM);
    float4 a = xr[lane];
    float4 b = xr[lane + 64];
    float ss = a.x*a.x + a.y*a.y + a.z*a.z + a.w*a.w
             + b.x*b.x + b.y*b.y + b.z*b.z + b.w*b.w;
    #pragma unroll
    for (int off = 32; off > 0; off >>= 1) ss += __shfl_xor(ss, off, 64);
    float s = 22.62741699796952f / fmaxf(sqrtf(ss), 1e-8f);
    const float4* gr = (const float4*)gamma;
    float4 g1 = gr[lane], g2 = gr[lane + 64];
    bf16x4 o1 = { (__bf16)(a.x*g1.x*s), (__bf16)(a.y*g1.y*s),
                  (__bf16)(a.z*g1.z*s), (__bf16)(a.w*g1.w*s) };
    bf16x4 o2 = { (__bf16)(b.x*g2.x*s), (__bf16)(b.y*g2.y*s),
                  (__bf16)(b.z*g2.z*s), (__bf16)(b.w*g2.w*s) };
    *(bf16x4*)(A + (size_t)row * DIM + lane * 4)       = o1;
    *(bf16x4*)(A + (size_t)row * DIM + 256 + lane * 4) = o2;
}

// ---------------- weight transpose-cast tile (64k x 64n) ----------------
__device__ __forceinline__ void tcast_tile(const float* __restrict__ W,
                                           __bf16* __restrict__ Wt,
                                           int K, int N, int n0, int k0, int t,
                                           float (*Ls)[68]) {
    const int tx = t & 15, ty = t >> 4;
    #pragma unroll
    for (int i = 0; i < 4; i++) {
        int k = ty + i * 16;
        float4 v = *(const float4*)&W[(size_t)(k0 + k) * N + n0 + tx * 4];
        *(float4*)&Ls[k][tx * 4] = v;
    }
    __syncthreads();
    const int nrow = t >> 2, seg = (t & 3) * 16;
    bf16x8 o0, o1;
    #pragma unroll
    for (int j = 0; j < 8; j++) o0[j] = (__bf16)Ls[seg + j][nrow];
    #pragma unroll
    for (int j = 0; j < 8; j++) o1[j] = (__bf16)Ls[seg + 8 + j][nrow];
    *(bf16x8*)&Wt[(size_t)(n0 + nrow) * K + k0 + seg]     = o0;
    *(bf16x8*)&Wt[(size_t)(n0 + nrow) * K + k0 + seg + 8] = o1;
}

// ---------------- 128x128-tile MFMA GEMM body (m97 structure, 16 KB LDS) -------
template <int N, typename OutT>
__device__ __forceinline__ void gemm128x128(const __bf16* __restrict__ A,
                                            const __bf16* __restrict__ Bt,
                                            OutT* __restrict__ C,
                                            int row0, int col0, char* smraw) {
    __bf16* As = (__bf16*)smraw;            // 8 KB
    __bf16* Bs = (__bf16*)(smraw + 8192);   // 8 KB
    const int t = threadIdx.x;
    const int lane = t & 63;
    const int w = t >> 6;
    const int l16 = lane & 15, quad = lane >> 4;
    const int wr = w >> 1, wc = w & 1;

    f32x4 acc[4][4] = {};
    const int r0a = t >> 2,         ks0 = (t & 3) * 8;
    const int r1a = (t + 256) >> 2, ks1 = (t & 3) * 8;

    for (int kt = 0; kt < DIM; kt += 32) {
        __syncthreads();
        GLOAD_LDS16(A  + (size_t)(row0 + r0a) * DIM + kt + ks0, As + t * 8);
        GLOAD_LDS16(A  + (size_t)(row0 + r1a) * DIM + kt + ks1, As + (t + 256) * 8);
        GLOAD_LDS16(Bt + (size_t)(col0 + r0a) * DIM + kt + ks0, Bs + t * 8);
        GLOAD_LDS16(Bt + (size_t)(col0 + r1a) * DIM + kt + ks1, Bs + (t + 256) * 8);
        __syncthreads();
        bf16x8 af[4], bfr[4];
        #pragma unroll
        for (int mi = 0; mi < 4; mi++)
            af[mi] = *(const bf16x8*)(As + (wr * 64 + mi * 16 + l16) * 32 + quad * 8);
        #pragma unroll
        for (int ni = 0; ni < 4; ni++)
            bfr[ni] = *(const bf16x8*)(Bs + (wc * 64 + ni * 16 + l16) * 32 + quad * 8);
        #pragma unroll
        for (int mi = 0; mi < 4; mi++)
            #pragma unroll
            for (int ni = 0; ni < 4; ni++)
                acc[mi][ni] = MFMA_BF16(af[mi], bfr[ni], acc[mi][ni], 0, 0, 0);
    }
    #pragma unroll
    for (int mi = 0; mi < 4; mi++)
        #pragma unroll
        for (int ni = 0; ni < 4; ni++)
            #pragma unroll
            for (int r = 0; r < 4; r++) {
                int m = row0 + wr * 64 + mi * 16 + quad * 4 + r;
                int n = col0 + wc * 64 + ni * 16 + l16;
                if constexpr (sizeof(OutT) == 4) C[(size_t)m * N + n] = acc[mi][ni][r];
                else                             C[(size_t)m * N + n] = (__bf16)acc[mi][ni][r];
            }
}

// ---------------- 64x128-tile MFMA GEMM body (12 KB LDS) ----------------
template <int N, typename OutT>
__device__ __forceinline__ void gemm64x128(const __bf16* __restrict__ A,
                                           const __bf16* __restrict__ Bt,
                                           OutT* __restrict__ C,
                                           int row0, int col0, char* smraw) {
    __bf16* As = (__bf16*)smraw;             // 4 KB
    __bf16* Bs = (__bf16*)(smraw + 4096);    // 8 KB
    const int t = threadIdx.x;
    const int lane = t & 63;
    const int w = t >> 6;
    const int l16 = lane & 15, quad = lane >> 4;
    const int wr = w >> 1, wc = w & 1;       // wave tile: 32 rows x 64 cols

    f32x4 acc[2][4] = {};
    const int r0a = t >> 2, ks0 = (t & 3) * 8;
    const int r1a = (t + 256) >> 2;

    for (int kt = 0; kt < DIM; kt += 32) {
        __syncthreads();
        GLOAD_LDS16(A  + (size_t)(row0 + r0a) * DIM + kt + ks0, As + t * 8);
        GLOAD_LDS16(Bt + (size_t)(col0 + r0a) * DIM + kt + ks0, Bs + t * 8);
        GLOAD_LDS16(Bt + (size_t)(col0 + r1a) * DIM + kt + ks0, Bs + (t + 256) * 8);
        __syncthreads();
        bf16x8 af[2], bfr[4];
        #pragma unroll
        for (int mi = 0; mi < 2; mi++)
            af[mi] = *(const bf16x8*)(As + (wr * 32 + mi * 16 + l16) * 32 + quad * 8);
        #pragma unroll
        for (int ni = 0; ni < 4; ni++)
            bfr[ni] = *(const bf16x8*)(Bs + (wc * 64 + ni * 16 + l16) * 32 + quad * 8);
        #pragma unroll
        for (int mi = 0; mi < 2; mi++)
            #pragma unroll
            for (int ni = 0; ni < 4; ni++)
                acc[mi][ni] = MFMA_BF16(af[mi], bfr[ni], acc[mi][ni], 0, 0, 0);
    }
    #pragma unroll
    for (int mi = 0; mi < 2; mi++)
        #pragma unroll
        for (int ni = 0; ni < 4; ni++)
            #pragma unroll
            for (int r = 0; r < 4; r++) {
                int m = row0 + wr * 32 + mi * 16 + quad * 4 + r;
                int n = col0 + wc * 64 + ni * 16 + l16;
                if constexpr (sizeof(OutT) == 4) C[(size_t)m * N + n] = acc[mi][ni][r];
                else                             C[(size_t)m * N + n] = (__bf16)acc[mi][ni][r];
            }
}

// ---------------- prep body: RoPE + head-major Q + fragmented K, key-permuted V^T
__device__ __forceinline__ void prep_body(const __bf16* __restrict__ qkvb,
                                          __bf16* __restrict__ Qb,
                                          __bf16* __restrict__ Kf,
                                          __bf16* __restrict__ Vf,
                                          int bx, int t) {
    const int nt = bx & 31;
    const int bh = bx >> 5;
    const int b  = bh >> 3;
    const int h  = bh & 7;
    const float QSCALE = 0.18033688011112042f;   // 0.125 * log2(e)

    {   // Q/K rope: thread t -> row r = t>>2, dims d0 = (t&3)*16 (8 pairs)
        const int r  = t >> 2;
        const int d0 = (t & 3) << 4;
        const int pos = nt * 64 + r;
        const __bf16* qp = qkvb + (size_t)(b * N_SEQ + pos) * QKV_N + h * DH + d0;

        union Pack { __bf16 h[16]; uint4 u[2]; };
        Pack qi, ki, qo, ko;
        qi.u[0] = ((const uint4*)qp)[0];         qi.u[1] = ((const uint4*)qp)[1];
        ki.u[0] = ((const uint4*)(qp + 512))[0]; ki.u[1] = ((const uint4*)(qp + 512))[1];

        #pragma unroll
        for (int i = 0; i < 8; i++) {
            int p = (d0 >> 1) + i;
            float inv = exp2f(-0.41524101186092028f * (float)p);  // 10000^(-p/32)
            float ang = (float)pos * inv;
            float sn, cs;
            sincosf(ang, &sn, &cs);
            float qe = (float)qi.h[2*i], qd = (float)qi.h[2*i+1];
            float ke = (float)ki.h[2*i], kd = (float)ki.h[2*i+1];
            qo.h[2*i]   = (__bf16)(QSCALE * (qe * cs - qd * sn));
            qo.h[2*i+1] = (__bf16)(QSCALE * (qd * cs + qe * sn));
            ko.h[2*i]   = (__bf16)(ke * cs - kd * sn);
            ko.h[2*i+1] = (__bf16)(kd * cs + ke * sn);
        }
        uint4* qd_ = (uint4*)(Qb + ((size_t)bh * N_SEQ + pos) * DH + d0);
        qd_[0] = qo.u[0]; qd_[1] = qo.u[1];
        const int group = r >> 4, kl = r & 15;
        const int c = d0 >> 5, quad = (d0 & 31) >> 3;
        __bf16* kdst = Kf + ((size_t)bh * 32 + nt) * 4096
                          + (group * 2 + c) * 512 + (quad * 16 + kl) * 8;
        *(uint4*)kdst         = ko.u[0];
        *(uint4*)(kdst + 128) = ko.u[1];   // quad+1
    }

    {   // V: wave w -> keys w*16..+15, lane = dim 0..63; key-permuted V^T
        const int w = t >> 6, lane = t & 63;
        union PackV { __bf16 h[16]; unsigned long long q[4]; };
        PackV v;
        #pragma unroll
        for (int j = 0; j < 16; j++) {
            int row = nt * 64 + w * 16 + j;
            v.h[j] = qkvb[(size_t)(b * N_SEQ + row) * QKV_N + 1024 + h * DH + lane];
        }
        const int ng = lane >> 4, vl = lane & 15;
        __bf16* vdst = Vf + ((size_t)bh * 32 + nt) * 4096
                          + (ng * 2 + (w >> 1)) * 512 + vl * 8 + (w & 1) * 4;
        #pragma unroll
        for (int q = 0; q < 4; q++)
            *(unsigned long long*)(vdst + q * 128) = v.q[q];
    }
}

// ---------------- attention body (R4 structure, best measured ~42.8 us) --------
__device__ __forceinline__ void attn_body(const __bf16* __restrict__ Qb,
                                          const __bf16* __restrict__ Kf,
                                          const __bf16* __restrict__ Vf,
                                          __bf16* __restrict__ attn,
                                          int bx, int t, char* smraw) {
    __bf16 (*kv)[2][8192] = reinterpret_cast<__bf16 (*)[2][8192]>(smraw);  // 64 KB

    const int w    = t >> 6;
    const int lane = t & 63;
    const int l16  = lane & 15;
    const int quad = lane >> 4;
    const int qh   = w >> 1;       // query half (0: q0..63, 1: q64..127)
    const int kp   = w & 1;        // key parity (tiles 2i+kp)

    const int bh = bx & 31;
    const int qc = bx >> 5;        // 0..15 (128 queries each)
    const int b  = bh >> 3;
    const int h  = bh & 7;

    const int qrow0 = qc * 128 + qh * 64;
    const __bf16* Qh = Qb + ((size_t)bh * N_SEQ + qrow0) * DH;
    const __bf16* Kt = Kf + (size_t)bh * 32 * 4096;
    const __bf16* Vt = Vf + (size_t)bh * 32 * 4096;

    bf16x8 qa[4][2];
    #pragma unroll
    for (int f = 0; f < 4; f++) {
        qa[f][0] = *(const bf16x8*)(Qh + (size_t)(f * 16 + l16) * DH + quad * 8);
        qa[f][1] = *(const bf16x8*)(Qh + (size_t)(f * 16 + l16) * DH + 32 + quad * 8);
    }

    bf16x8 ones;
    #pragma unroll
    for (int i = 0; i < 8; i++) ones[i] = (__bf16)1.0f;

    f32x4 O[4][4] = {};
    f32x4 L[4] = {};

    auto dma_tile = [&](int tidx, int p, int pp) {   // tidx = 64-key tile (0..31)
        const __bf16* kss = Kt + (size_t)tidx * 4096;
        const __bf16* vss = Vt + (size_t)tidx * 4096;
        __bf16* dst = &kv[p][pp][0];
        GLOAD_LDS16(kss + t * 8,        dst + t * 8);
        GLOAD_LDS16(kss + 2048 + t * 8, dst + 2048 + t * 8);
        GLOAD_LDS16(vss + t * 8,        dst + 4096 + t * 8);
        GLOAD_LDS16(vss + 2048 + t * 8, dst + 4096 + 2048 + t * 8);
    };

    dma_tile(0, 0, 0);
    dma_tile(1, 1, 0);
    for (int i = 0; i < 16; i++) {           // 16 tile-pairs
        const int cur = i & 1;
        SBAR();                              // A: all waves done reading pp[cur^1]
        if (i + 1 < 16) {
            dma_tile(2 * (i + 1),     0, cur ^ 1);   // prefetch next pair
            dma_tile(2 * (i + 1) + 1, 1, cur ^ 1);   // (8 loads stay in flight)
            asm volatile("s_waitcnt vmcnt(8)" ::: "memory");  // pair i (mine) done
        } else {
            asm volatile("s_waitcnt vmcnt(0)" ::: "memory");
        }
        SBAR();                              // B: publish pair i to all waves

        const __bf16* kb = &kv[kp][cur][0];
        const __bf16* vb = &kv[kp][cur][4096];

        bf16x8 kf[4][2];
        #pragma unroll
        for (int g = 0; g < 4; g++)
            #pragma unroll
            for (int c = 0; c < 2; c++)
                kf[g][c] = *(const bf16x8*)(kb + (g * 2 + c) * 512 + lane * 8);

        bf16x8 pa[4][2];
        #pragma unroll
        for (int f = 0; f < 4; f++) {
            f32x4 S[4];
            __builtin_amdgcn_s_setprio(1);
            #pragma unroll
            for (int g = 0; g < 4; g++) {
                f32x4 z = {0, 0, 0, 0};
                z = MFMA_BF16(kf[g][0], qa[f][0], z, 0, 0, 0);
                z = MFMA_BF16(kf[g][1], qa[f][1], z, 0, 0, 0);
                S[g] = z;
            }
            __builtin_amdgcn_s_setprio(0);
            // lane l16 = query; S[g][r] = P(query=l16, key=g*16+4*quad+r)
            #pragma unroll
            for (int j = 0; j < 8; j++) {
                pa[f][0][j] = (__bf16)__builtin_amdgcn_exp2f(S[(j >> 2)][j & 3]);
                pa[f][1][j] = (__bf16)__builtin_amdgcn_exp2f(S[2 + (j >> 2)][j & 3]);
            }
        }

        bf16x8 vf[4][2];
        #pragma unroll
        for (int n = 0; n < 4; n++)
            #pragma unroll
            for (int kc = 0; kc < 2; kc++)
                vf[n][kc] = *(const bf16x8*)(vb + (n * 2 + kc) * 512 + lane * 8);

        __builtin_amdgcn_s_setprio(1);
        #pragma unroll
        for (int f = 0; f < 4; f++) {
            #pragma unroll
            for (int n = 0; n < 4; n++) {
                O[f][n] = MFMA_BF16(pa[f][0], vf[n][0], O[f][n], 0, 0, 0);
                O[f][n] = MFMA_BF16(pa[f][1], vf[n][1], O[f][n], 0, 0, 0);
            }
            L[f] = MFMA_BF16(pa[f][0], ones, L[f], 0, 0, 0);
            L[f] = MFMA_BF16(pa[f][1], ones, L[f], 0, 0, 0);
        }
        __builtin_amdgcn_s_setprio(0);
    }

    // ---- cross-parity reduction (padded strides 68/20 f32, no bank conflicts)
    __syncthreads();
    float* reds = (float*)smraw;
    float* myO = reds + (size_t)(qh * 64 + lane) * 68;
    float* myL = reds + 128 * 68 + (size_t)(qh * 64 + lane) * 20;
    if (kp == 1) {
        #pragma unroll
        for (int f = 0; f < 4; f++) {
            #pragma unroll
            for (int n = 0; n < 4; n++)
                *(f32x4*)(myO + (f * 4 + n) * 4) = O[f][n];
            *(f32x4*)(myL + f * 4) = L[f];
        }
    }
    __syncthreads();
    if (kp == 0) {
        #pragma unroll
        for (int f = 0; f < 4; f++) {
            #pragma unroll
            for (int n = 0; n < 4; n++)
                O[f][n] += *(const f32x4*)(myO + (f * 4 + n) * 4);
            L[f] += *(const f32x4*)(myL + f * 4);
        }
        #pragma unroll
        for (int f = 0; f < 4; f++) {
            float inv[4];
            #pragma unroll
            for (int r = 0; r < 4; r++) inv[r] = 1.0f / L[f][r];
            #pragma unroll
            for (int n = 0; n < 4; n++)
                #pragma unroll
                for (int r = 0; r < 4; r++) {
                    size_t row = (size_t)(b * N_SEQ + qrow0 + f * 16 + quad * 4 + r);
                    attn[row * 512 + h * DH + n * 16 + l16] =
                        (__bf16)(O[f][n][r] * inv[r]);
                }
        }
    }
}

// ================= classic (fallback) kernels — R4-proven =================
__global__ __launch_bounds__(256) void prelude_kernel(const float* __restrict__ x,
                                                      const float* __restrict__ gamma,
                                                      const float* __restrict__ w_qkv,
                                                      const float* __restrict__ w_out,
                                                      __bf16* __restrict__ A,
                                                      __bf16* __restrict__ Wqkvt,
                                                      __bf16* __restrict__ Woutt) {
    __shared__ float Ls[64][68];
    const int bx = blockIdx.x, t = threadIdx.x;
    if (bx < 2048) {
        rms_body(x, gamma, A, bx, t);
    } else {
        const int idx = bx - 2048;          // 0..255
        const int k0 = (idx >> 5) * 64, c = idx & 31;
        if (c < 24) tcast_tile(w_qkv, Wqkvt, DIM, QKV_N, c * 64, k0, t, Ls);
        else        tcast_tile(w_out, Woutt, DIM, DIM, (c - 24) * 64, k0, t, Ls);
    }
}

__global__ __launch_bounds__(256) void gemm_qkv_kernel(const __bf16* __restrict__ A,
                                                       const __bf16* __restrict__ Bt,
                                                       __bf16* __restrict__ C) {
    __shared__ __align__(16) char sm[16384];
    gemm128x128<QKV_N, __bf16>(A, Bt, C, blockIdx.y * 128, blockIdx.x * 128, sm);
}

__global__ __launch_bounds__(256) void prep_kernel(const __bf16* __restrict__ qkvb,
                                                   __bf16* __restrict__ Qb,
                                                   __bf16* __restrict__ Kf,
                                                   __bf16* __restrict__ Vf) {
    prep_body(qkvb, Qb, Kf, Vf, blockIdx.x, threadIdx.x);
}

__global__ __launch_bounds__(256, 2) void attn_mfma_kernel(const __bf16* __restrict__ Qb,
                                                           const __bf16* __restrict__ Kf,
                                                           const __bf16* __restrict__ Vf,
                                                           __bf16* __restrict__ attn) {
    __shared__ __align__(16) char sm[65536];
    attn_body(Qb, Kf, Vf, attn, blockIdx.x, threadIdx.x, sm);
}

__global__ __launch_bounds__(256) void gemm_out_kernel(const __bf16* __restrict__ A,
                                                       const __bf16* __restrict__ Bt,
                                                       float* __restrict__ C) {
    __shared__ __align__(16) char sm[12288];
    gemm64x128<DIM, float>(A, Bt, C, blockIdx.y * 64, blockIdx.x * 128, sm);
}

// ================= cooperative mega-kernels (grid 512, 2 blocks/CU slack) ======
__global__ __launch_bounds__(256, 2) void mega1(const float* __restrict__ x,
                                                const float* __restrict__ gamma,
                                                const float* __restrict__ w_qkv,
                                                const float* __restrict__ w_out,
                                                __bf16* __restrict__ Abf,
                                                __bf16* __restrict__ Wqkvt,
                                                __bf16* __restrict__ Woutt,
                                                __bf16* __restrict__ qkvb,
                                                __bf16* __restrict__ Qb,
                                                __bf16* __restrict__ Kf,
                                                __bf16* __restrict__ Vf) {
    __shared__ __align__(16) char sm[17408];
    cg::grid_group grid = cg::this_grid();
    const int bid = blockIdx.x, t = threadIdx.x;

    // phase A: rms-cast (vb<2048) + weight tcast (vb 2048..2303); step 512
    for (int vb = bid; vb < 2304; vb += 512) {
        if (vb < 2048) {
            rms_body(x, gamma, Abf, vb, t);
        } else {
            const int idx = vb - 2048;
            float (*Ls)[68] = reinterpret_cast<float (*)[68]>(sm);
            const int k0 = (idx >> 5) * 64, c = idx & 31;
            if (c < 24) tcast_tile(w_qkv, Wqkvt, DIM, QKV_N, c * 64, k0, t, Ls);
            else        tcast_tile(w_out, Woutt, DIM, DIM, (c - 24) * 64, k0, t, Ls);
        }
    }
    grid.sync();

    // phase B: QKV GEMM 8192x1536x512, 128x128 tiles (768 tiles, 1.5 passes)
    for (int vb = bid; vb < 768; vb += 512)
        gemm128x128<QKV_N, __bf16>(Abf, Wqkvt, qkvb, (vb / 12) * 128, (vb % 12) * 128, sm);
    grid.sync();

    // phase C: prep (RoPE + fragment), 1024 vb
    for (int vb = bid; vb < 1024; vb += 512)
        prep_body(qkvb, Qb, Kf, Vf, vb, t);
}

__global__ __launch_bounds__(256, 2) void mega2(const __bf16* __restrict__ Qb,
                                                const __bf16* __restrict__ Kf,
                                                const __bf16* __restrict__ Vf,
                                                __bf16* __restrict__ attnb,
                                                const __bf16* __restrict__ Woutt,
                                                float* __restrict__ out) {
    __shared__ __align__(16) char sm[65536];
    cg::grid_group grid = cg::this_grid();
    attn_body(Qb, Kf, Vf, attnb, blockIdx.x, threadIdx.x, sm);
    grid.sync();
    const int vb = blockIdx.x;     // 128 row-tiles x 4 col-tiles
    gemm64x128<DIM, float>(attnb, Woutt, out, (vb >> 2) * 64, (vb & 3) * 128, sm);
}

extern "C" void kernel_launch(void* const* d_in, const int* in_sizes, int n_in,
                              void* d_out, int out_size, void* d_ws, size_t ws_size,
                              hipStream_t stream) {
    const float* x     = (const float*)d_in[0];
    const float* gamma = (const float*)d_in[1];
    const float* w_qkv = (const float*)d_in[2];
    const float* w_out = (const float*)d_in[3];
    float* out = (float*)d_out;

    __bf16* Abf   = (__bf16*)d_ws;
    __bf16* Wqkvt = Abf + (size_t)ROWS * DIM;
    __bf16* Woutt = Wqkvt + (size_t)QKV_N * DIM;
    __bf16* qkvb  = Woutt + (size_t)DIM * DIM;
    __bf16* attnb = qkvb;
    __bf16* Qb    = qkvb + (size_t)ROWS * QKV_N;
    __bf16* Kf    = Qb + (size_t)NH * B_SZ * N_SEQ * DH;
    __bf16* Vf    = Kf + (size_t)NH * B_SZ * N_SEQ * DH;

    void* a1[] = { (void*)&x, (void*)&gamma, (void*)&w_qkv, (void*)&w_out,
                   (void*)&Abf, (void*)&Wqkvt, (void*)&Woutt, (void*)&qkvb,
                   (void*)&Qb, (void*)&Kf, (void*)&Vf };
    void* a2[] = { (void*)&Qb, (void*)&Kf, (void*)&Vf, (void*)&attnb,
                   (void*)&Woutt, (void*)&out };

    bool m1 = hipLaunchCooperativeKernel(reinterpret_cast<void*>(mega1),
                                         dim3(512), dim3(256), a1, 0, stream)
              == hipSuccess;
    if (!m1) {
        prelude_kernel<<<2304, 256, 0, stream>>>(x, gamma, w_qkv, w_out,
                                                 Abf, Wqkvt, Woutt);
        gemm_qkv_kernel<<<dim3(QKV_N / 128, ROWS / 128), 256, 0, stream>>>(
            Abf, Wqkvt, qkvb);
        prep_kernel<<<1024, 256, 0, stream>>>(qkvb, Qb, Kf, Vf);
    }

    bool m2 = m1 && hipLaunchCooperativeKernel(reinterpret_cast<void*>(mega2),
                                               dim3(512), dim3(256), a2, 0, stream)
                    == hipSuccess;
    if (!m2) {
        attn_mfma_kernel<<<512, 256, 0, stream>>>(Qb, Kf, Vf, attnb);
        gemm_out_kernel<<<dim3(4, 128), 256, 0, stream>>>(attnb, Woutt, out);
    }
}

// Round 8
// 153.139 us; speedup vs baseline: 2.4765x; 2.4765x over previous
//
#include <hip/hip_runtime.h>
#include <hip/hip_bf16.h>
#include <cmath>

#define B_SZ 4
#define N_SEQ 2048
#define DIM 512
#define NH 8
#define DH 64
#define QKV_N 1536
#define ROWS (B_SZ * N_SEQ)   // 8192

typedef __bf16 bf16x8 __attribute__((ext_vector_type(8)));
typedef __bf16 bf16x4 __attribute__((ext_vector_type(4)));
typedef float  f32x4  __attribute__((ext_vector_type(4)));

#define GLOAD_LDS16(gp, lp)                                                     \
    __builtin_amdgcn_global_load_lds(                                           \
        (const __attribute__((address_space(1))) void*)(gp),                    \
        (__attribute__((address_space(3))) void*)(lp), 16, 0, 0)

#define MFMA_BF16 __builtin_amdgcn_mfma_f32_16x16x32_bf16

// raw workgroup barrier WITHOUT the compiler's implicit vmcnt(0)/lgkmcnt(0) drain
#define SBAR() asm volatile("s_barrier" ::: "memory")

// ---------------- prelude: rmscast (blocks 0..2047, 4 rows each) + weight
// transpose-casts (blocks 2048..2303) in ONE launch.
__device__ __forceinline__ void tcast_tile(const float* __restrict__ W,
                                           __bf16* __restrict__ Wt,
                                           int K, int N, int n0, int k0, int t,
                                           float (*Ls)[68]) {
    const int tx = t & 15, ty = t >> 4;
    #pragma unroll
    for (int i = 0; i < 4; i++) {
        int k = ty + i * 16;
        float4 v = *(const float4*)&W[(size_t)(k0 + k) * N + n0 + tx * 4];
        *(float4*)&Ls[k][tx * 4] = v;
    }
    __syncthreads();
    const int nrow = t >> 2, seg = (t & 3) * 16;
    bf16x8 o0, o1;
    #pragma unroll
    for (int j = 0; j < 8; j++) o0[j] = (__bf16)Ls[seg + j][nrow];
    #pragma unroll
    for (int j = 0; j < 8; j++) o1[j] = (__bf16)Ls[seg + 8 + j][nrow];
    *(bf16x8*)&Wt[(size_t)(n0 + nrow) * K + k0 + seg]     = o0;
    *(bf16x8*)&Wt[(size_t)(n0 + nrow) * K + k0 + seg + 8] = o1;
}

__global__ __launch_bounds__(256) void prelude_kernel(const float* __restrict__ x,
                                                      const float* __restrict__ gamma,
                                                      const float* __restrict__ w_qkv,
                                                      const float* __restrict__ w_out,
                                                      __bf16* __restrict__ A,
                                                      __bf16* __restrict__ Wqkvt,
                                                      __bf16* __restrict__ Woutt) {
    __shared__ float Ls[64][68];
    const int bx = blockIdx.x, t = threadIdx.x;
    if (bx < 2048) {
        // rms-norm + gamma + bf16 cast; one wave per row, 4 rows per block
        const int row  = bx * 4 + (t >> 6);
        const int lane = t & 63;
        const float4* xr = (const float4*)(x + (size_t)row * DIM);
        float4 a = xr[lane];
        float4 b = xr[lane + 64];
        float ss = a.x*a.x + a.y*a.y + a.z*a.z + a.w*a.w
                 + b.x*b.x + b.y*b.y + b.z*b.z + b.w*b.w;
        #pragma unroll
        for (int off = 32; off > 0; off >>= 1) ss += __shfl_xor(ss, off, 64);
        float s = 22.62741699796952f / fmaxf(sqrtf(ss), 1e-8f);
        const float4* gr = (const float4*)gamma;
        float4 g1 = gr[lane], g2 = gr[lane + 64];
        bf16x4 o1 = { (__bf16)(a.x*g1.x*s), (__bf16)(a.y*g1.y*s),
                      (__bf16)(a.z*g1.z*s), (__bf16)(a.w*g1.w*s) };
        bf16x4 o2 = { (__bf16)(b.x*g2.x*s), (__bf16)(b.y*g2.y*s),
                      (__bf16)(b.z*g2.z*s), (__bf16)(b.w*g2.w*s) };
        *(bf16x4*)(A + (size_t)row * DIM + lane * 4)       = o1;
        *(bf16x4*)(A + (size_t)row * DIM + 256 + lane * 4) = o2;
    } else {
        const int idx = bx - 2048;          // 0..255
        const int k0 = (idx >> 5) * 64, c = idx & 31;
        if (c < 24) tcast_tile(w_qkv, Wqkvt, DIM, QKV_N, c * 64, k0, t, Ls);
        else        tcast_tile(w_out, Woutt, DIM, DIM, (c - 24) * 64, k0, t, Ls);
    }
}

// ---------------- QKV GEMM, 128x128 tile, DOUBLE-BUFFERED (R8):
// raw s_barrier + counted vmcnt(4) keeps next K-step's 4 global_load_lds in
// flight across the current step's whole compute (the __syncthreads version
// force-drained them serially 16x per block — R4-attn lesson applied here).
template <int N, typename OutT>
__global__ __launch_bounds__(256) void gemm_bf16_kernel(const __bf16* __restrict__ A,
                                                        const __bf16* __restrict__ Bt,
                                                        OutT* __restrict__ C) {
    __shared__ __bf16 As[2][128 * 32];   // 16 KB
    __shared__ __bf16 Bs[2][128 * 32];   // 16 KB  (32 KB total -> 3+ blocks/CU)
    const int t = threadIdx.x;
    const int lane = t & 63;
    const int w = t >> 6;
    const int l16 = lane & 15, quad = lane >> 4;
    const int wr = w >> 1, wc = w & 1;
    const int row0 = blockIdx.y * 128, col0 = blockIdx.x * 128;

    f32x4 acc[4][4] = {};

    const int r0a = t >> 2,         ks0 = (t & 3) * 8;
    const int r1a = (t + 256) >> 2;

    auto dma = [&](int kidx, int bb) {      // stage K-step kidx into buf bb
        const int kt = kidx * 32;
        GLOAD_LDS16(A  + (size_t)(row0 + r0a) * DIM + kt + ks0, As[bb] + t * 8);
        GLOAD_LDS16(A  + (size_t)(row0 + r1a) * DIM + kt + ks0, As[bb] + (t + 256) * 8);
        GLOAD_LDS16(Bt + (size_t)(col0 + r0a) * DIM + kt + ks0, Bs[bb] + t * 8);
        GLOAD_LDS16(Bt + (size_t)(col0 + r1a) * DIM + kt + ks0, Bs[bb] + (t + 256) * 8);
    };

    dma(0, 0);
    for (int i = 0; i < 16; i++) {
        const int cur = i & 1;
        SBAR();                              // A: all waves done reading buf[cur^1]
        if (i + 1 < 16) {
            dma(i + 1, cur ^ 1);             // prefetch (4 loads stay in flight)
            asm volatile("s_waitcnt vmcnt(4)" ::: "memory");   // step i (mine) done
        } else {
            asm volatile("s_waitcnt vmcnt(0)" ::: "memory");
        }
        SBAR();                              // B: publish step i to all waves

        bf16x8 af[4], bfr[4];
        #pragma unroll
        for (int mi = 0; mi < 4; mi++)
            af[mi] = *(const bf16x8*)(As[cur] + (wr * 64 + mi * 16 + l16) * 32 + quad * 8);
        #pragma unroll
        for (int ni = 0; ni < 4; ni++)
            bfr[ni] = *(const bf16x8*)(Bs[cur] + (wc * 64 + ni * 16 + l16) * 32 + quad * 8);
        __builtin_amdgcn_s_setprio(1);
        #pragma unroll
        for (int mi = 0; mi < 4; mi++)
            #pragma unroll
            for (int ni = 0; ni < 4; ni++)
                acc[mi][ni] = MFMA_BF16(af[mi], bfr[ni], acc[mi][ni], 0, 0, 0);
        __builtin_amdgcn_s_setprio(0);
    }
    #pragma unroll
    for (int mi = 0; mi < 4; mi++) {
        #pragma unroll
        for (int ni = 0; ni < 4; ni++) {
            #pragma unroll
            for (int r = 0; r < 4; r++) {
                int m = row0 + wr * 64 + mi * 16 + quad * 4 + r;
                int n = col0 + wc * 64 + ni * 16 + l16;
                if constexpr (sizeof(OutT) == 4) {
                    C[(size_t)m * N + n] = acc[mi][ni][r];
                } else {
                    C[(size_t)m * N + n] = (__bf16)acc[mi][ni][r];
                }
            }
        }
    }
}

// ---------------- out-projection GEMM, 64x128 tile, DOUBLE-BUFFERED (R8).
__global__ __launch_bounds__(256) void gemm_out_kernel(const __bf16* __restrict__ A,
                                                       const __bf16* __restrict__ Bt,
                                                       float* __restrict__ C) {
    __shared__ __bf16 As[2][64 * 32];    // 8 KB
    __shared__ __bf16 Bs[2][128 * 32];   // 16 KB  (24 KB total)
    const int t = threadIdx.x;
    const int lane = t & 63;
    const int w = t >> 6;
    const int l16 = lane & 15, quad = lane >> 4;
    const int wr = w >> 1, wc = w & 1;   // wave tile: 32 rows x 64 cols
    const int row0 = blockIdx.y * 64, col0 = blockIdx.x * 128;

    f32x4 acc[2][4] = {};

    const int r0a = t >> 2, ks0 = (t & 3) * 8;
    const int r1a = (t + 256) >> 2;

    auto dma = [&](int kidx, int bb) {
        const int kt = kidx * 32;
        GLOAD_LDS16(A  + (size_t)(row0 + r0a) * DIM + kt + ks0, As[bb] + t * 8);
        GLOAD_LDS16(Bt + (size_t)(col0 + r0a) * DIM + kt + ks0, Bs[bb] + t * 8);
        GLOAD_LDS16(Bt + (size_t)(col0 + r1a) * DIM + kt + ks0, Bs[bb] + (t + 256) * 8);
    };

    dma(0, 0);
    for (int i = 0; i < 16; i++) {
        const int cur = i & 1;
        SBAR();                              // A: all waves done reading buf[cur^1]
        if (i + 1 < 16) {
            dma(i + 1, cur ^ 1);
            asm volatile("s_waitcnt vmcnt(3)" ::: "memory");   // step i (mine) done
        } else {
            asm volatile("s_waitcnt vmcnt(0)" ::: "memory");
        }
        SBAR();                              // B: publish step i

        bf16x8 af[2], bfr[4];
        #pragma unroll
        for (int mi = 0; mi < 2; mi++)
            af[mi] = *(const bf16x8*)(As[cur] + (wr * 32 + mi * 16 + l16) * 32 + quad * 8);
        #pragma unroll
        for (int ni = 0; ni < 4; ni++)
            bfr[ni] = *(const bf16x8*)(Bs[cur] + (wc * 64 + ni * 16 + l16) * 32 + quad * 8);
        __builtin_amdgcn_s_setprio(1);
        #pragma unroll
        for (int mi = 0; mi < 2; mi++)
            #pragma unroll
            for (int ni = 0; ni < 4; ni++)
                acc[mi][ni] = MFMA_BF16(af[mi], bfr[ni], acc[mi][ni], 0, 0, 0);
        __builtin_amdgcn_s_setprio(0);
    }
    #pragma unroll
    for (int mi = 0; mi < 2; mi++)
        #pragma unroll
        for (int ni = 0; ni < 4; ni++)
            #pragma unroll
            for (int r = 0; r < 4; r++) {
                int m = row0 + wr * 32 + mi * 16 + quad * 4 + r;
                int n = col0 + wc * 64 + ni * 16 + l16;
                C[(size_t)m * 512 + n] = acc[mi][ni][r];
            }
}

// ---------------- Prep: fused RoPE + head-major bf16 Q + PRE-FRAGMENTED K and V^T.
// Q scale = 0.125 * log2(e): attention uses raw v_exp_f32 (exp2) directly.
// V fragment key-permutation matches the swapped-QK in-register P layout:
//   vf[n][c] element j at lane(quad,l16) = V[32c + 16*(j>>2) + 4*quad + (j&3)][n*16+l16]
__global__ __launch_bounds__(256) void prep_kernel(const __bf16* __restrict__ qkvb,
                                                   __bf16* __restrict__ Qb,
                                                   __bf16* __restrict__ Kf,
                                                   __bf16* __restrict__ Vf) {
    const int bx = blockIdx.x;   // bh*32 + ntile
    const int nt = bx & 31;
    const int bh = bx >> 5;
    const int b  = bh >> 3;
    const int h  = bh & 7;
    const int t  = threadIdx.x;
    const float QSCALE = 0.18033688011112042f;   // 0.125 * log2(e)

    {   // Q/K rope: thread t -> row r = t>>2, dims d0 = (t&3)*16 (8 pairs)
        const int r  = t >> 2;
        const int d0 = (t & 3) << 4;
        const int pos = nt * 64 + r;
        const __bf16* qp = qkvb + (size_t)(b * N_SEQ + pos) * QKV_N + h * DH + d0;

        union Pack { __bf16 h[16]; uint4 u[2]; };
        Pack qi, ki, qo, ko;
        qi.u[0] = ((const uint4*)qp)[0];         qi.u[1] = ((const uint4*)qp)[1];
        ki.u[0] = ((const uint4*)(qp + 512))[0]; ki.u[1] = ((const uint4*)(qp + 512))[1];

        #pragma unroll
        for (int i = 0; i < 8; i++) {
            int p = (d0 >> 1) + i;
            float inv = exp2f(-0.41524101186092028f * (float)p);  // 10000^(-p/32)
            float ang = (float)pos * inv;
            float sn, cs;
            sincosf(ang, &sn, &cs);
            float qe = (float)qi.h[2*i], qd = (float)qi.h[2*i+1];
            float ke = (float)ki.h[2*i], kd = (float)ki.h[2*i+1];
            qo.h[2*i]   = (__bf16)(QSCALE * (qe * cs - qd * sn));
            qo.h[2*i+1] = (__bf16)(QSCALE * (qd * cs + qe * sn));
            ko.h[2*i]   = (__bf16)(ke * cs - kd * sn);
            ko.h[2*i+1] = (__bf16)(kd * cs + ke * sn);
        }
        // Q: row-major
        uint4* qd_ = (uint4*)(Qb + ((size_t)bh * N_SEQ + pos) * DH + d0);
        qd_[0] = qo.u[0]; qd_[1] = qo.u[1];
        // K: fragmented (chunk (g*2+c), elem (quad*16+kl)*8+j)
        const int group = r >> 4, kl = r & 15;
        const int c = d0 >> 5, quad = (d0 & 31) >> 3;
        __bf16* kdst = Kf + ((size_t)bh * 32 + nt) * 4096
                          + (group * 2 + c) * 512 + (quad * 16 + kl) * 8;
        *(uint4*)kdst         = ko.u[0];
        *(uint4*)(kdst + 128) = ko.u[1];   // quad+1
    }

    {   // V: wave w -> keys w*16..+15, lane = dim 0..63; write key-permuted V^T
        // key k = w*16+jj: kc=k[5]=w>>1, quad=k[3:2]=jj>>2, j = (k[4]<<2)|k[1:0]
        //                  = ((w&1)<<2)|(jj&3)  -> four contiguous b64 stores.
        const int w = t >> 6, lane = t & 63;
        union PackV { __bf16 h[16]; unsigned long long q[4]; };
        PackV v;
        #pragma unroll
        for (int j = 0; j < 16; j++) {
            int row = nt * 64 + w * 16 + j;
            v.h[j] = qkvb[(size_t)(b * N_SEQ + row) * QKV_N + 1024 + h * DH + lane];
        }
        const int ng = lane >> 4, vl = lane & 15;
        __bf16* vdst = Vf + ((size_t)bh * 32 + nt) * 4096
                          + (ng * 2 + (w >> 1)) * 512 + vl * 8 + (w & 1) * 4;
        #pragma unroll
        for (int q = 0; q < 4; q++)
            *(unsigned long long*)(vdst + q * 128) = v.q[q];
    }
}

// ---------------- MFMA flash attention (R4 structure, best measured ~42.8 us).
__global__ __launch_bounds__(256, 2) void attn_mfma_kernel(const __bf16* __restrict__ Qb,
                                                           const __bf16* __restrict__ Kf,
                                                           const __bf16* __restrict__ Vf,
                                                           __bf16* __restrict__ attn) {
    __shared__ __bf16 kv[2][2][8192];    // [parity][pingpong][K(4096)|V(4096)] = 64 KB

    const int t    = threadIdx.x;
    const int w    = t >> 6;
    const int lane = t & 63;
    const int l16  = lane & 15;
    const int quad = lane >> 4;
    const int qh   = w >> 1;       // query half (0: q0..63, 1: q64..127)
    const int kp   = w & 1;        // key parity (tiles 2i+kp)

    const int bx = blockIdx.x;     // qc*32 + bh
    const int bh = bx & 31;
    const int qc = bx >> 5;        // 0..15 (128 queries each)
    const int b  = bh >> 3;
    const int h  = bh & 7;

    const int qrow0 = qc * 128 + qh * 64;
    const __bf16* Qh = Qb + ((size_t)bh * N_SEQ + qrow0) * DH;
    const __bf16* Kt = Kf + (size_t)bh * 32 * 4096;
    const __bf16* Vt = Vf + (size_t)bh * 32 * 4096;

    bf16x8 qa[4][2];
    #pragma unroll
    for (int f = 0; f < 4; f++) {
        qa[f][0] = *(const bf16x8*)(Qh + (size_t)(f * 16 + l16) * DH + quad * 8);
        qa[f][1] = *(const bf16x8*)(Qh + (size_t)(f * 16 + l16) * DH + 32 + quad * 8);
    }

    bf16x8 ones;
    #pragma unroll
    for (int i = 0; i < 8; i++) ones[i] = (__bf16)1.0f;

    f32x4 O[4][4] = {};
    f32x4 L[4] = {};

    auto dma_tile = [&](int tidx, int p, int pp) {   // tidx = 64-key tile (0..31)
        const __bf16* kss = Kt + (size_t)tidx * 4096;
        const __bf16* vss = Vt + (size_t)tidx * 4096;
        __bf16* dst = &kv[p][pp][0];
        GLOAD_LDS16(kss + t * 8,        dst + t * 8);
        GLOAD_LDS16(kss + 2048 + t * 8, dst + 2048 + t * 8);
        GLOAD_LDS16(vss + t * 8,        dst + 4096 + t * 8);
        GLOAD_LDS16(vss + 2048 + t * 8, dst + 4096 + 2048 + t * 8);
    };

    dma_tile(0, 0, 0);
    dma_tile(1, 1, 0);
    for (int i = 0; i < 16; i++) {           // 16 tile-pairs
        const int cur = i & 1;
        SBAR();                              // A: all waves done reading pp[cur^1]
        if (i + 1 < 16) {
            dma_tile(2 * (i + 1),     0, cur ^ 1);   // prefetch next pair
            dma_tile(2 * (i + 1) + 1, 1, cur ^ 1);   // (8 loads stay in flight)
            asm volatile("s_waitcnt vmcnt(8)" ::: "memory");  // pair i (mine) done
        } else {
            asm volatile("s_waitcnt vmcnt(0)" ::: "memory");
        }
        SBAR();                              // B: publish pair i to all waves

        const __bf16* kb = &kv[kp][cur][0];
        const __bf16* vb = &kv[kp][cur][4096];

        bf16x8 kf[4][2];
        #pragma unroll
        for (int g = 0; g < 4; g++)
            #pragma unroll
            for (int c = 0; c < 2; c++)
                kf[g][c] = *(const bf16x8*)(kb + (g * 2 + c) * 512 + lane * 8);

        bf16x8 pa[4][2];
        #pragma unroll
        for (int f = 0; f < 4; f++) {
            f32x4 S[4];
            __builtin_amdgcn_s_setprio(1);
            #pragma unroll
            for (int g = 0; g < 4; g++) {
                f32x4 z = {0, 0, 0, 0};
                z = MFMA_BF16(kf[g][0], qa[f][0], z, 0, 0, 0);
                z = MFMA_BF16(kf[g][1], qa[f][1], z, 0, 0, 0);
                S[g] = z;
            }
            __builtin_amdgcn_s_setprio(0);
            // lane l16 = query; S[g][r] = P(query=l16, key=g*16+4*quad+r)
            #pragma unroll
            for (int j = 0; j < 8; j++) {
                pa[f][0][j] = (__bf16)__builtin_amdgcn_exp2f(S[(j >> 2)][j & 3]);
                pa[f][1][j] = (__bf16)__builtin_amdgcn_exp2f(S[2 + (j >> 2)][j & 3]);
            }
        }

        bf16x8 vf[4][2];
        #pragma unroll
        for (int n = 0; n < 4; n++)
            #pragma unroll
            for (int kc = 0; kc < 2; kc++)
                vf[n][kc] = *(const bf16x8*)(vb + (n * 2 + kc) * 512 + lane * 8);

        __builtin_amdgcn_s_setprio(1);
        #pragma unroll
        for (int f = 0; f < 4; f++) {
            #pragma unroll
            for (int n = 0; n < 4; n++) {
                O[f][n] = MFMA_BF16(pa[f][0], vf[n][0], O[f][n], 0, 0, 0);
                O[f][n] = MFMA_BF16(pa[f][1], vf[n][1], O[f][n], 0, 0, 0);
            }
            L[f] = MFMA_BF16(pa[f][0], ones, L[f], 0, 0, 0);
            L[f] = MFMA_BF16(pa[f][1], ones, L[f], 0, 0, 0);
        }
        __builtin_amdgcn_s_setprio(0);
    }

    // ---- cross-parity reduction (padded strides 68/20 f32, no bank conflicts)
    __syncthreads();
    float* reds = (float*)&kv[0][0][0];
    float* myO = reds + (size_t)(qh * 64 + lane) * 68;
    float* myL = reds + 128 * 68 + (size_t)(qh * 64 + lane) * 20;
    if (kp == 1) {
        #pragma unroll
        for (int f = 0; f < 4; f++) {
            #pragma unroll
            for (int n = 0; n < 4; n++)
                *(f32x4*)(myO + (f * 4 + n) * 4) = O[f][n];
            *(f32x4*)(myL + f * 4) = L[f];
        }
    }
    __syncthreads();
    if (kp == 0) {
        #pragma unroll
        for (int f = 0; f < 4; f++) {
            #pragma unroll
            for (int n = 0; n < 4; n++)
                O[f][n] += *(const f32x4*)(myO + (f * 4 + n) * 4);
            L[f] += *(const f32x4*)(myL + f * 4);
        }
        #pragma unroll
        for (int f = 0; f < 4; f++) {
            float inv[4];
            #pragma unroll
            for (int r = 0; r < 4; r++) inv[r] = 1.0f / L[f][r];
            #pragma unroll
            for (int n = 0; n < 4; n++)
                #pragma unroll
                for (int r = 0; r < 4; r++) {
                    size_t row = (size_t)(b * N_SEQ + qrow0 + f * 16 + quad * 4 + r);
                    attn[row * 512 + h * DH + n * 16 + l16] =
                        (__bf16)(O[f][n][r] * inv[r]);
                }
        }
    }
}

extern "C" void kernel_launch(void* const* d_in, const int* in_sizes, int n_in,
                              void* d_out, int out_size, void* d_ws, size_t ws_size,
                              hipStream_t stream) {
    const float* x     = (const float*)d_in[0];
    const float* gamma = (const float*)d_in[1];
    const float* w_qkv = (const float*)d_in[2];
    const float* w_out = (const float*)d_in[3];
    float* out = (float*)d_out;

    // workspace (bf16): Abf 8.4MB (attnb aliases it after gemm1) | Wqkvt 1.5 |
    // Woutt 0.5 | qkvb 25.2 (dead after prep) | Qb,Kf,Vf 8.4 each.  ~61 MB (proven).
    __bf16* Abf   = (__bf16*)d_ws;
    __bf16* Wqkvt = Abf + (size_t)ROWS * DIM;
    __bf16* Woutt = Wqkvt + (size_t)QKV_N * DIM;
    __bf16* qkvb  = Woutt + (size_t)DIM * DIM;
    __bf16* attnb = qkvb;
    __bf16* Qb    = qkvb + (size_t)ROWS * QKV_N;
    __bf16* Kf    = Qb + (size_t)NH * B_SZ * N_SEQ * DH;
    __bf16* Vf    = Kf + (size_t)NH * B_SZ * N_SEQ * DH;

    prelude_kernel<<<2304, 256, 0, stream>>>(x, gamma, w_qkv, w_out,
                                             Abf, Wqkvt, Woutt);
    gemm_bf16_kernel<QKV_N, __bf16><<<dim3(QKV_N / 128, ROWS / 128), 256, 0, stream>>>(
        Abf, Wqkvt, qkvb);
    prep_kernel<<<1024, 256, 0, stream>>>(qkvb, Qb, Kf, Vf);
    attn_mfma_kernel<<<512, 256, 0, stream>>>(Qb, Kf, Vf, attnb);
    gemm_out_kernel<<<dim3(4, 128), 256, 0, stream>>>(attnb, Woutt, out);
}

// Round 9
// 151.965 us; speedup vs baseline: 2.4956x; 1.0077x over previous
//
#include <hip/hip_runtime.h>
#include <hip/hip_bf16.h>
#include <cmath>

#define B_SZ 4
#define N_SEQ 2048
#define DIM 512
#define NH 8
#define DH 64
#define QKV_N 1536
#define ROWS (B_SZ * N_SEQ)   // 8192

typedef __bf16 bf16x8 __attribute__((ext_vector_type(8)));
typedef __bf16 bf16x4 __attribute__((ext_vector_type(4)));
typedef float  f32x4  __attribute__((ext_vector_type(4)));

#define GLOAD_LDS16(gp, lp)                                                     \
    __builtin_amdgcn_global_load_lds(                                           \
        (const __attribute__((address_space(1))) void*)(gp),                    \
        (__attribute__((address_space(3))) void*)(lp), 16, 0, 0)

#define MFMA_BF16 __builtin_amdgcn_mfma_f32_16x16x32_bf16

// raw workgroup barrier WITHOUT the compiler's implicit vmcnt(0)/lgkmcnt(0) drain
#define SBAR() asm volatile("s_barrier" ::: "memory")

// ---------------- prelude: rmscast (blocks 0..2047, 4 rows each) + weight
// transpose-casts (blocks 2048..2303) in ONE launch.
__device__ __forceinline__ void tcast_tile(const float* __restrict__ W,
                                           __bf16* __restrict__ Wt,
                                           int K, int N, int n0, int k0, int t,
                                           float (*Ls)[68]) {
    const int tx = t & 15, ty = t >> 4;
    #pragma unroll
    for (int i = 0; i < 4; i++) {
        int k = ty + i * 16;
        float4 v = *(const float4*)&W[(size_t)(k0 + k) * N + n0 + tx * 4];
        *(float4*)&Ls[k][tx * 4] = v;
    }
    __syncthreads();
    const int nrow = t >> 2, seg = (t & 3) * 16;
    bf16x8 o0, o1;
    #pragma unroll
    for (int j = 0; j < 8; j++) o0[j] = (__bf16)Ls[seg + j][nrow];
    #pragma unroll
    for (int j = 0; j < 8; j++) o1[j] = (__bf16)Ls[seg + 8 + j][nrow];
    *(bf16x8*)&Wt[(size_t)(n0 + nrow) * K + k0 + seg]     = o0;
    *(bf16x8*)&Wt[(size_t)(n0 + nrow) * K + k0 + seg + 8] = o1;
}

__global__ __launch_bounds__(256) void prelude_kernel(const float* __restrict__ x,
                                                      const float* __restrict__ gamma,
                                                      const float* __restrict__ w_qkv,
                                                      const float* __restrict__ w_out,
                                                      __bf16* __restrict__ A,
                                                      __bf16* __restrict__ Wqkvt,
                                                      __bf16* __restrict__ Woutt) {
    __shared__ float Ls[64][68];
    const int bx = blockIdx.x, t = threadIdx.x;
    if (bx < 2048) {
        // rms-norm + gamma + bf16 cast; one wave per row, 4 rows per block
        const int row  = bx * 4 + (t >> 6);
        const int lane = t & 63;
        const float4* xr = (const float4*)(x + (size_t)row * DIM);
        float4 a = xr[lane];
        float4 b = xr[lane + 64];
        float ss = a.x*a.x + a.y*a.y + a.z*a.z + a.w*a.w
                 + b.x*b.x + b.y*b.y + b.z*b.z + b.w*b.w;
        #pragma unroll
        for (int off = 32; off > 0; off >>= 1) ss += __shfl_xor(ss, off, 64);
        float s = 22.62741699796952f / fmaxf(sqrtf(ss), 1e-8f);
        const float4* gr = (const float4*)gamma;
        float4 g1 = gr[lane], g2 = gr[lane + 64];
        bf16x4 o1 = { (__bf16)(a.x*g1.x*s), (__bf16)(a.y*g1.y*s),
                      (__bf16)(a.z*g1.z*s), (__bf16)(a.w*g1.w*s) };
        bf16x4 o2 = { (__bf16)(b.x*g2.x*s), (__bf16)(b.y*g2.y*s),
                      (__bf16)(b.z*g2.z*s), (__bf16)(b.w*g2.w*s) };
        *(bf16x4*)(A + (size_t)row * DIM + lane * 4)       = o1;
        *(bf16x4*)(A + (size_t)row * DIM + 256 + lane * 4) = o2;
    } else {
        const int idx = bx - 2048;          // 0..255
        const int k0 = (idx >> 5) * 64, c = idx & 31;
        if (c < 24) tcast_tile(w_qkv, Wqkvt, DIM, QKV_N, c * 64, k0, t, Ls);
        else        tcast_tile(w_out, Woutt, DIM, DIM, (c - 24) * 64, k0, t, Ls);
    }
}

// ---------------- QKV GEMM, 128x128 tile, 3-DEEP pipeline (R9):
// triple-buffered LDS, prefetch distance = 2 K-steps (~700cy > L2 latency),
// vmcnt(8) completes only the oldest step's 4 loads.  R8's 1-step depth was
// neutral because ~350cy of compute couldn't cover the load latency.
// V-column blocks (blockIdx.x >= 8) write attention-ready fragmented Vf
// DIRECTLY from the accumulator (register repack: kc=mi>>1, j>>2=mi&1,
// j&3=r — bit-identical values to the old prep path), eliminating the
// qkvb round-trip and prep's V gather.
__global__ __launch_bounds__(256) void gemm_qkv_kernel(const __bf16* __restrict__ A,
                                                       const __bf16* __restrict__ Bt,
                                                       __bf16* __restrict__ C,
                                                       __bf16* __restrict__ Vf) {
    __shared__ __bf16 As[3][128 * 32];   // 24 KB
    __shared__ __bf16 Bs[3][128 * 32];   // 24 KB  (48 KB -> 3 blocks/CU)
    const int t = threadIdx.x;
    const int lane = t & 63;
    const int w = t >> 6;
    const int l16 = lane & 15, quad = lane >> 4;
    const int wr = w >> 1, wc = w & 1;
    const int row0 = blockIdx.y * 128, col0 = blockIdx.x * 128;

    f32x4 acc[4][4] = {};

    const int r0a = t >> 2, ks0 = (t & 3) * 8;
    const int r1a = (t + 256) >> 2;

    auto dma = [&](int kidx, int bb) {      // stage K-step kidx into buf bb
        const int kt = kidx * 32;
        GLOAD_LDS16(A  + (size_t)(row0 + r0a) * DIM + kt + ks0, As[bb] + t * 8);
        GLOAD_LDS16(A  + (size_t)(row0 + r1a) * DIM + kt + ks0, As[bb] + (t + 256) * 8);
        GLOAD_LDS16(Bt + (size_t)(col0 + r0a) * DIM + kt + ks0, Bs[bb] + t * 8);
        GLOAD_LDS16(Bt + (size_t)(col0 + r1a) * DIM + kt + ks0, Bs[bb] + (t + 256) * 8);
    };

    dma(0, 0);
    dma(1, 1);
    int cb = 0, wb = 2;
    for (int i = 0; i < 16; i++) {
        SBAR();                              // A: all waves done computing step i-1
        if (i + 2 < 16) {
            dma(i + 2, wb);                  // issue 2-ahead (8 loads stay in flight)
            asm volatile("s_waitcnt vmcnt(8)" ::: "memory");   // oldest (step i) done
        } else if (i + 1 < 16) {
            asm volatile("s_waitcnt vmcnt(4)" ::: "memory");
        } else {
            asm volatile("s_waitcnt vmcnt(0)" ::: "memory");
        }
        SBAR();                              // B: everyone's step-i loads done

        bf16x8 af[4], bfr[4];
        #pragma unroll
        for (int mi = 0; mi < 4; mi++)
            af[mi] = *(const bf16x8*)(As[cb] + (wr * 64 + mi * 16 + l16) * 32 + quad * 8);
        #pragma unroll
        for (int ni = 0; ni < 4; ni++)
            bfr[ni] = *(const bf16x8*)(Bs[cb] + (wc * 64 + ni * 16 + l16) * 32 + quad * 8);
        __builtin_amdgcn_s_setprio(1);
        #pragma unroll
        for (int mi = 0; mi < 4; mi++)
            #pragma unroll
            for (int ni = 0; ni < 4; ni++)
                acc[mi][ni] = MFMA_BF16(af[mi], bfr[ni], acc[mi][ni], 0, 0, 0);
        __builtin_amdgcn_s_setprio(0);
        cb = (cb == 2) ? 0 : cb + 1;
        wb = (wb == 2) ? 0 : wb + 1;
    }

    if (blockIdx.x >= 8) {
        // V tile: write fragmented Vf directly (layout-verified vs prep).
        const int head  = (blockIdx.x - 8) * 2 + wc;
        const int mbase = row0 + wr * 64;
        const int b     = mbase >> 11;
        const int nt    = (mbase >> 6) & 31;
        __bf16* vt = Vf + ((size_t)(b * 8 + head) * 32 + nt) * 4096;
        #pragma unroll
        for (int ni = 0; ni < 4; ni++)
            #pragma unroll
            for (int kc = 0; kc < 2; kc++) {
                bf16x8 o = { (__bf16)acc[2*kc][ni][0],   (__bf16)acc[2*kc][ni][1],
                             (__bf16)acc[2*kc][ni][2],   (__bf16)acc[2*kc][ni][3],
                             (__bf16)acc[2*kc+1][ni][0], (__bf16)acc[2*kc+1][ni][1],
                             (__bf16)acc[2*kc+1][ni][2], (__bf16)acc[2*kc+1][ni][3] };
                *(bf16x8*)(vt + (ni * 2 + kc) * 512 + lane * 8) = o;
            }
    } else {
        #pragma unroll
        for (int mi = 0; mi < 4; mi++)
            #pragma unroll
            for (int ni = 0; ni < 4; ni++)
                #pragma unroll
                for (int r = 0; r < 4; r++) {
                    int m = row0 + wr * 64 + mi * 16 + quad * 4 + r;
                    int n = col0 + wc * 64 + ni * 16 + l16;
                    C[(size_t)m * QKV_N + n] = (__bf16)acc[mi][ni][r];
                }
    }
}

// ---------------- out-projection GEMM, 64x128 tile, 3-DEEP pipeline (R9).
__global__ __launch_bounds__(256) void gemm_out_kernel(const __bf16* __restrict__ A,
                                                       const __bf16* __restrict__ Bt,
                                                       float* __restrict__ C) {
    __shared__ __bf16 As[3][64 * 32];    // 12 KB
    __shared__ __bf16 Bs[3][128 * 32];   // 24 KB  (36 KB total)
    const int t = threadIdx.x;
    const int lane = t & 63;
    const int w = t >> 6;
    const int l16 = lane & 15, quad = lane >> 4;
    const int wr = w >> 1, wc = w & 1;   // wave tile: 32 rows x 64 cols
    const int row0 = blockIdx.y * 64, col0 = blockIdx.x * 128;

    f32x4 acc[2][4] = {};

    const int r0a = t >> 2, ks0 = (t & 3) * 8;
    const int r1a = (t + 256) >> 2;

    auto dma = [&](int kidx, int bb) {
        const int kt = kidx * 32;
        GLOAD_LDS16(A  + (size_t)(row0 + r0a) * DIM + kt + ks0, As[bb] + t * 8);
        GLOAD_LDS16(Bt + (size_t)(col0 + r0a) * DIM + kt + ks0, Bs[bb] + t * 8);
        GLOAD_LDS16(Bt + (size_t)(col0 + r1a) * DIM + kt + ks0, Bs[bb] + (t + 256) * 8);
    };

    dma(0, 0);
    dma(1, 1);
    int cb = 0, wb = 2;
    for (int i = 0; i < 16; i++) {
        SBAR();                              // A: all waves done computing step i-1
        if (i + 2 < 16) {
            dma(i + 2, wb);
            asm volatile("s_waitcnt vmcnt(6)" ::: "memory");   // oldest (step i) done
        } else if (i + 1 < 16) {
            asm volatile("s_waitcnt vmcnt(3)" ::: "memory");
        } else {
            asm volatile("s_waitcnt vmcnt(0)" ::: "memory");
        }
        SBAR();                              // B: publish step i

        bf16x8 af[2], bfr[4];
        #pragma unroll
        for (int mi = 0; mi < 2; mi++)
            af[mi] = *(const bf16x8*)(As[cb] + (wr * 32 + mi * 16 + l16) * 32 + quad * 8);
        #pragma unroll
        for (int ni = 0; ni < 4; ni++)
            bfr[ni] = *(const bf16x8*)(Bs[cb] + (wc * 64 + ni * 16 + l16) * 32 + quad * 8);
        __builtin_amdgcn_s_setprio(1);
        #pragma unroll
        for (int mi = 0; mi < 2; mi++)
            #pragma unroll
            for (int ni = 0; ni < 4; ni++)
                acc[mi][ni] = MFMA_BF16(af[mi], bfr[ni], acc[mi][ni], 0, 0, 0);
        __builtin_amdgcn_s_setprio(0);
        cb = (cb == 2) ? 0 : cb + 1;
        wb = (wb == 2) ? 0 : wb + 1;
    }
    #pragma unroll
    for (int mi = 0; mi < 2; mi++)
        #pragma unroll
        for (int ni = 0; ni < 4; ni++)
            #pragma unroll
            for (int r = 0; r < 4; r++) {
                int m = row0 + wr * 32 + mi * 16 + quad * 4 + r;
                int n = col0 + wc * 64 + ni * 16 + l16;
                C[(size_t)m * 512 + n] = acc[mi][ni][r];
            }
}

// ---------------- Prep (R9: Q/K only — V handled by the GEMM epilogue).
// Fused RoPE + head-major bf16 Q + PRE-FRAGMENTED K.
// Q scale = 0.125 * log2(e): attention uses raw v_exp_f32 (exp2) directly.
__global__ __launch_bounds__(256) void prep_kernel(const __bf16* __restrict__ qkvb,
                                                   __bf16* __restrict__ Qb,
                                                   __bf16* __restrict__ Kf) {
    const int bx = blockIdx.x;   // bh*32 + ntile
    const int nt = bx & 31;
    const int bh = bx >> 5;
    const int b  = bh >> 3;
    const int h  = bh & 7;
    const int t  = threadIdx.x;
    const float QSCALE = 0.18033688011112042f;   // 0.125 * log2(e)

    // Q/K rope: thread t -> row r = t>>2, dims d0 = (t&3)*16 (8 pairs)
    const int r  = t >> 2;
    const int d0 = (t & 3) << 4;
    const int pos = nt * 64 + r;
    const __bf16* qp = qkvb + (size_t)(b * N_SEQ + pos) * QKV_N + h * DH + d0;

    union Pack { __bf16 h[16]; uint4 u[2]; };
    Pack qi, ki, qo, ko;
    qi.u[0] = ((const uint4*)qp)[0];         qi.u[1] = ((const uint4*)qp)[1];
    ki.u[0] = ((const uint4*)(qp + 512))[0]; ki.u[1] = ((const uint4*)(qp + 512))[1];

    #pragma unroll
    for (int i = 0; i < 8; i++) {
        int p = (d0 >> 1) + i;
        float inv = exp2f(-0.41524101186092028f * (float)p);  // 10000^(-p/32)
        float ang = (float)pos * inv;
        float sn, cs;
        sincosf(ang, &sn, &cs);
        float qe = (float)qi.h[2*i], qd = (float)qi.h[2*i+1];
        float ke = (float)ki.h[2*i], kd = (float)ki.h[2*i+1];
        qo.h[2*i]   = (__bf16)(QSCALE * (qe * cs - qd * sn));
        qo.h[2*i+1] = (__bf16)(QSCALE * (qd * cs + qe * sn));
        ko.h[2*i]   = (__bf16)(ke * cs - kd * sn);
        ko.h[2*i+1] = (__bf16)(kd * cs + ke * sn);
    }
    // Q: row-major
    uint4* qd_ = (uint4*)(Qb + ((size_t)bh * N_SEQ + pos) * DH + d0);
    qd_[0] = qo.u[0]; qd_[1] = qo.u[1];
    // K: fragmented (chunk (g*2+c), elem (quad*16+kl)*8+j)
    const int group = r >> 4, kl = r & 15;
    const int c = d0 >> 5, quad = (d0 & 31) >> 3;
    __bf16* kdst = Kf + ((size_t)bh * 32 + nt) * 4096
                      + (group * 2 + c) * 512 + (quad * 16 + kl) * 8;
    *(uint4*)kdst         = ko.u[0];
    *(uint4*)(kdst + 128) = ko.u[1];   // quad+1
}

// ---------------- MFMA flash attention (R4 structure, best measured ~42.8 us).
__global__ __launch_bounds__(256, 2) void attn_mfma_kernel(const __bf16* __restrict__ Qb,
                                                           const __bf16* __restrict__ Kf,
                                                           const __bf16* __restrict__ Vf,
                                                           __bf16* __restrict__ attn) {
    __shared__ __bf16 kv[2][2][8192];    // [parity][pingpong][K(4096)|V(4096)] = 64 KB

    const int t    = threadIdx.x;
    const int w    = t >> 6;
    const int lane = t & 63;
    const int l16  = lane & 15;
    const int quad = lane >> 4;
    const int qh   = w >> 1;       // query half (0: q0..63, 1: q64..127)
    const int kp   = w & 1;        // key parity (tiles 2i+kp)

    const int bx = blockIdx.x;     // qc*32 + bh
    const int bh = bx & 31;
    const int qc = bx >> 5;        // 0..15 (128 queries each)
    const int b  = bh >> 3;
    const int h  = bh & 7;

    const int qrow0 = qc * 128 + qh * 64;
    const __bf16* Qh = Qb + ((size_t)bh * N_SEQ + qrow0) * DH;
    const __bf16* Kt = Kf + (size_t)bh * 32 * 4096;
    const __bf16* Vt = Vf + (size_t)bh * 32 * 4096;

    bf16x8 qa[4][2];
    #pragma unroll
    for (int f = 0; f < 4; f++) {
        qa[f][0] = *(const bf16x8*)(Qh + (size_t)(f * 16 + l16) * DH + quad * 8);
        qa[f][1] = *(const bf16x8*)(Qh + (size_t)(f * 16 + l16) * DH + 32 + quad * 8);
    }

    bf16x8 ones;
    #pragma unroll
    for (int i = 0; i < 8; i++) ones[i] = (__bf16)1.0f;

    f32x4 O[4][4] = {};
    f32x4 L[4] = {};

    auto dma_tile = [&](int tidx, int p, int pp) {   // tidx = 64-key tile (0..31)
        const __bf16* kss = Kt + (size_t)tidx * 4096;
        const __bf16* vss = Vt + (size_t)tidx * 4096;
        __bf16* dst = &kv[p][pp][0];
        GLOAD_LDS16(kss + t * 8,        dst + t * 8);
        GLOAD_LDS16(kss + 2048 + t * 8, dst + 2048 + t * 8);
        GLOAD_LDS16(vss + t * 8,        dst + 4096 + t * 8);
        GLOAD_LDS16(vss + 2048 + t * 8, dst + 4096 + 2048 + t * 8);
    };

    dma_tile(0, 0, 0);
    dma_tile(1, 1, 0);
    for (int i = 0; i < 16; i++) {           // 16 tile-pairs
        const int cur = i & 1;
        SBAR();                              // A: all waves done reading pp[cur^1]
        if (i + 1 < 16) {
            dma_tile(2 * (i + 1),     0, cur ^ 1);   // prefetch next pair
            dma_tile(2 * (i + 1) + 1, 1, cur ^ 1);   // (8 loads stay in flight)
            asm volatile("s_waitcnt vmcnt(8)" ::: "memory");  // pair i (mine) done
        } else {
            asm volatile("s_waitcnt vmcnt(0)" ::: "memory");
        }
        SBAR();                              // B: publish pair i to all waves

        const __bf16* kb = &kv[kp][cur][0];
        const __bf16* vb = &kv[kp][cur][4096];

        bf16x8 kf[4][2];
        #pragma unroll
        for (int g = 0; g < 4; g++)
            #pragma unroll
            for (int c = 0; c < 2; c++)
                kf[g][c] = *(const bf16x8*)(kb + (g * 2 + c) * 512 + lane * 8);

        bf16x8 pa[4][2];
        #pragma unroll
        for (int f = 0; f < 4; f++) {
            f32x4 S[4];
            __builtin_amdgcn_s_setprio(1);
            #pragma unroll
            for (int g = 0; g < 4; g++) {
                f32x4 z = {0, 0, 0, 0};
                z = MFMA_BF16(kf[g][0], qa[f][0], z, 0, 0, 0);
                z = MFMA_BF16(kf[g][1], qa[f][1], z, 0, 0, 0);
                S[g] = z;
            }
            __builtin_amdgcn_s_setprio(0);
            // lane l16 = query; S[g][r] = P(query=l16, key=g*16+4*quad+r)
            #pragma unroll
            for (int j = 0; j < 8; j++) {
                pa[f][0][j] = (__bf16)__builtin_amdgcn_exp2f(S[(j >> 2)][j & 3]);
                pa[f][1][j] = (__bf16)__builtin_amdgcn_exp2f(S[2 + (j >> 2)][j & 3]);
            }
        }

        bf16x8 vf[4][2];
        #pragma unroll
        for (int n = 0; n < 4; n++)
            #pragma unroll
            for (int kc = 0; kc < 2; kc++)
                vf[n][kc] = *(const bf16x8*)(vb + (n * 2 + kc) * 512 + lane * 8);

        __builtin_amdgcn_s_setprio(1);
        #pragma unroll
        for (int f = 0; f < 4; f++) {
            #pragma unroll
            for (int n = 0; n < 4; n++) {
                O[f][n] = MFMA_BF16(pa[f][0], vf[n][0], O[f][n], 0, 0, 0);
                O[f][n] = MFMA_BF16(pa[f][1], vf[n][1], O[f][n], 0, 0, 0);
            }
            L[f] = MFMA_BF16(pa[f][0], ones, L[f], 0, 0, 0);
            L[f] = MFMA_BF16(pa[f][1], ones, L[f], 0, 0, 0);
        }
        __builtin_amdgcn_s_setprio(0);
    }

    // ---- cross-parity reduction (padded strides 68/20 f32, no bank conflicts)
    __syncthreads();
    float* reds = (float*)&kv[0][0][0];
    float* myO = reds + (size_t)(qh * 64 + lane) * 68;
    float* myL = reds + 128 * 68 + (size_t)(qh * 64 + lane) * 20;
    if (kp == 1) {
        #pragma unroll
        for (int f = 0; f < 4; f++) {
            #pragma unroll
            for (int n = 0; n < 4; n++)
                *(f32x4*)(myO + (f * 4 + n) * 4) = O[f][n];
            *(f32x4*)(myL + f * 4) = L[f];
        }
    }
    __syncthreads();
    if (kp == 0) {
        #pragma unroll
        for (int f = 0; f < 4; f++) {
            #pragma unroll
            for (int n = 0; n < 4; n++)
                O[f][n] += *(const f32x4*)(myO + (f * 4 + n) * 4);
            L[f] += *(const f32x4*)(myL + f * 4);
        }
        #pragma unroll
        for (int f = 0; f < 4; f++) {
            float inv[4];
            #pragma unroll
            for (int r = 0; r < 4; r++) inv[r] = 1.0f / L[f][r];
            #pragma unroll
            for (int n = 0; n < 4; n++)
                #pragma unroll
                for (int r = 0; r < 4; r++) {
                    size_t row = (size_t)(b * N_SEQ + qrow0 + f * 16 + quad * 4 + r);
                    attn[row * 512 + h * DH + n * 16 + l16] =
                        (__bf16)(O[f][n][r] * inv[r]);
                }
        }
    }
}

extern "C" void kernel_launch(void* const* d_in, const int* in_sizes, int n_in,
                              void* d_out, int out_size, void* d_ws, size_t ws_size,
                              hipStream_t stream) {
    const float* x     = (const float*)d_in[0];
    const float* gamma = (const float*)d_in[1];
    const float* w_qkv = (const float*)d_in[2];
    const float* w_out = (const float*)d_in[3];
    float* out = (float*)d_out;

    // workspace (bf16): Abf 8.4MB (attnb aliases it after gemm1) | Wqkvt 1.5 |
    // Woutt 0.5 | qkvb 25.2 (dead after prep) | Qb,Kf,Vf 8.4 each.  ~61 MB (proven).
    __bf16* Abf   = (__bf16*)d_ws;
    __bf16* Wqkvt = Abf + (size_t)ROWS * DIM;
    __bf16* Woutt = Wqkvt + (size_t)QKV_N * DIM;
    __bf16* qkvb  = Woutt + (size_t)DIM * DIM;
    __bf16* attnb = qkvb;
    __bf16* Qb    = qkvb + (size_t)ROWS * QKV_N;
    __bf16* Kf    = Qb + (size_t)NH * B_SZ * N_SEQ * DH;
    __bf16* Vf    = Kf + (size_t)NH * B_SZ * N_SEQ * DH;

    prelude_kernel<<<2304, 256, 0, stream>>>(x, gamma, w_qkv, w_out,
                                             Abf, Wqkvt, Woutt);
    gemm_qkv_kernel<<<dim3(QKV_N / 128, ROWS / 128), 256, 0, stream>>>(
        Abf, Wqkvt, qkvb, Vf);
    prep_kernel<<<1024, 256, 0, stream>>>(qkvb, Qb, Kf);
    attn_mfma_kernel<<<512, 256, 0, stream>>>(Qb, Kf, Vf, attnb);
    gemm_out_kernel<<<dim3(4, 128), 256, 0, stream>>>(attnb, Woutt, out);
}

// Round 11
// 150.808 us; speedup vs baseline: 2.5148x; 1.0077x over previous
//
#include <hip/hip_runtime.h>
#include <hip/hip_bf16.h>
#include <cmath>

#define B_SZ 4
#define N_SEQ 2048
#define DIM 512
#define NH 8
#define DH 64
#define QKV_N 1536
#define ROWS (B_SZ * N_SEQ)   // 8192

typedef __bf16 bf16x8 __attribute__((ext_vector_type(8)));
typedef __bf16 bf16x4 __attribute__((ext_vector_type(4)));
typedef float  f32x4  __attribute__((ext_vector_type(4)));

#define GLOAD_LDS16(gp, lp)                                                     \
    __builtin_amdgcn_global_load_lds(                                           \
        (const __attribute__((address_space(1))) void*)(gp),                    \
        (__attribute__((address_space(3))) void*)(lp), 16, 0, 0)

#define MFMA_BF16 __builtin_amdgcn_mfma_f32_16x16x32_bf16

// raw workgroup barrier WITHOUT the compiler's implicit vmcnt(0)/lgkmcnt(0) drain
#define SBAR() asm volatile("s_barrier" ::: "memory")

// ---------------- prelude: rmscast (blocks 0..2047, 4 rows each) + weight
// transpose-casts (blocks 2048..2303) in ONE launch.
__device__ __forceinline__ void tcast_tile(const float* __restrict__ W,
                                           __bf16* __restrict__ Wt,
                                           int K, int N, int n0, int k0, int t,
                                           float (*Ls)[68]) {
    const int tx = t & 15, ty = t >> 4;
    #pragma unroll
    for (int i = 0; i < 4; i++) {
        int k = ty + i * 16;
        float4 v = *(const float4*)&W[(size_t)(k0 + k) * N + n0 + tx * 4];
        *(float4*)&Ls[k][tx * 4] = v;
    }
    __syncthreads();
    const int nrow = t >> 2, seg = (t & 3) * 16;
    bf16x8 o0, o1;
    #pragma unroll
    for (int j = 0; j < 8; j++) o0[j] = (__bf16)Ls[seg + j][nrow];
    #pragma unroll
    for (int j = 0; j < 8; j++) o1[j] = (__bf16)Ls[seg + 8 + j][nrow];
    *(bf16x8*)&Wt[(size_t)(n0 + nrow) * K + k0 + seg]     = o0;
    *(bf16x8*)&Wt[(size_t)(n0 + nrow) * K + k0 + seg + 8] = o1;
}

__global__ __launch_bounds__(256) void prelude_kernel(const float* __restrict__ x,
                                                      const float* __restrict__ gamma,
                                                      const float* __restrict__ w_qkv,
                                                      const float* __restrict__ w_out,
                                                      __bf16* __restrict__ A,
                                                      __bf16* __restrict__ Wqkvt,
                                                      __bf16* __restrict__ Woutt) {
    __shared__ float Ls[64][68];
    const int bx = blockIdx.x, t = threadIdx.x;
    if (bx < 2048) {
        // rms-norm + gamma + bf16 cast; one wave per row, 4 rows per block
        const int row  = bx * 4 + (t >> 6);
        const int lane = t & 63;
        const float4* xr = (const float4*)(x + (size_t)row * DIM);
        float4 a = xr[lane];
        float4 b = xr[lane + 64];
        float ss = a.x*a.x + a.y*a.y + a.z*a.z + a.w*a.w
                 + b.x*b.x + b.y*b.y + b.z*b.z + b.w*b.w;
        #pragma unroll
        for (int off = 32; off > 0; off >>= 1) ss += __shfl_xor(ss, off, 64);
        float s = 22.62741699796952f / fmaxf(sqrtf(ss), 1e-8f);
        const float4* gr = (const float4*)gamma;
        float4 g1 = gr[lane], g2 = gr[lane + 64];
        bf16x4 o1 = { (__bf16)(a.x*g1.x*s), (__bf16)(a.y*g1.y*s),
                      (__bf16)(a.z*g1.z*s), (__bf16)(a.w*g1.w*s) };
        bf16x4 o2 = { (__bf16)(b.x*g2.x*s), (__bf16)(b.y*g2.y*s),
                      (__bf16)(b.z*g2.z*s), (__bf16)(b.w*g2.w*s) };
        *(bf16x4*)(A + (size_t)row * DIM + lane * 4)       = o1;
        *(bf16x4*)(A + (size_t)row * DIM + 256 + lane * 4) = o2;
    } else {
        const int idx = bx - 2048;          // 0..255
        const int k0 = (idx >> 5) * 64, c = idx & 31;
        if (c < 24) tcast_tile(w_qkv, Wqkvt, DIM, QKV_N, c * 64, k0, t, Ls);
        else        tcast_tile(w_out, Woutt, DIM, DIM, (c - 24) * 64, k0, t, Ls);
    }
}

// ---------------- QKV GEMM, 128x128 tile, 3-deep pipeline (R9) + FULLY FUSED
// epilogues (R10): qkvb is never materialized.
//   bx 0..3  (Q cols):   stage C-tile bf16 in LDS -> prep's RoPE verbatim ->
//                        Qb row-major (QSCALE applied).
//   bx 4..7  (K cols):   same -> Kf fragmented (no scale).
//   bx 8..11 (V cols):   direct fragmented Vf from accumulator (R9, proven).
// All values bit-identical to the old qkvb+prep path (same bf16 rounding
// points, same fp32 RoPE arithmetic).
__global__ __launch_bounds__(256) void gemm_qkv_kernel(const __bf16* __restrict__ A,
                                                       const __bf16* __restrict__ Bt,
                                                       __bf16* __restrict__ Qb,
                                                       __bf16* __restrict__ Kf,
                                                       __bf16* __restrict__ Vf) {
    __shared__ __align__(16) __bf16 smem[24576];   // 48 KB
    __bf16* As = smem;            // [3][4096]
    __bf16* Bs = smem + 12288;    // [3][4096]
    const int t = threadIdx.x;
    const int lane = t & 63;
    const int w = t >> 6;
    const int l16 = lane & 15, quad = lane >> 4;
    const int wr = w >> 1, wc = w & 1;
    const int row0 = blockIdx.y * 128, col0 = blockIdx.x * 128;

    f32x4 acc[4][4] = {};

    const int r0a = t >> 2, ks0 = (t & 3) * 8;
    const int r1a = (t + 256) >> 2;

    auto dma = [&](int kidx, int bb) {      // stage K-step kidx into buf bb
        const int kt = kidx * 32;
        GLOAD_LDS16(A  + (size_t)(row0 + r0a) * DIM + kt + ks0, As + bb * 4096 + t * 8);
        GLOAD_LDS16(A  + (size_t)(row0 + r1a) * DIM + kt + ks0, As + bb * 4096 + (t + 256) * 8);
        GLOAD_LDS16(Bt + (size_t)(col0 + r0a) * DIM + kt + ks0, Bs + bb * 4096 + t * 8);
        GLOAD_LDS16(Bt + (size_t)(col0 + r1a) * DIM + kt + ks0, Bs + bb * 4096 + (t + 256) * 8);
    };

    dma(0, 0);
    dma(1, 1);
    int cb = 0, wb = 2;
    for (int i = 0; i < 16; i++) {
        SBAR();                              // A: all waves done computing step i-1
        if (i + 2 < 16) {
            dma(i + 2, wb);                  // issue 2-ahead (8 loads stay in flight)
            asm volatile("s_waitcnt vmcnt(8)" ::: "memory");   // oldest (step i) done
        } else if (i + 1 < 16) {
            asm volatile("s_waitcnt vmcnt(4)" ::: "memory");
        } else {
            asm volatile("s_waitcnt vmcnt(0)" ::: "memory");
        }
        SBAR();                              // B: everyone's step-i loads done

        bf16x8 af[4], bfr[4];
        #pragma unroll
        for (int mi = 0; mi < 4; mi++)
            af[mi] = *(const bf16x8*)(As + cb * 4096 + (wr * 64 + mi * 16 + l16) * 32 + quad * 8);
        #pragma unroll
        for (int ni = 0; ni < 4; ni++)
            bfr[ni] = *(const bf16x8*)(Bs + cb * 4096 + (wc * 64 + ni * 16 + l16) * 32 + quad * 8);
        __builtin_amdgcn_s_setprio(1);
        #pragma unroll
        for (int mi = 0; mi < 4; mi++)
            #pragma unroll
            for (int ni = 0; ni < 4; ni++)
                acc[mi][ni] = MFMA_BF16(af[mi], bfr[ni], acc[mi][ni], 0, 0, 0);
        __builtin_amdgcn_s_setprio(0);
        cb = (cb == 2) ? 0 : cb + 1;
        wb = (wb == 2) ? 0 : wb + 1;
    }

    if (blockIdx.x >= 8) {
        // V tile: write fragmented Vf directly (R9, layout-verified vs prep).
        const int head  = (blockIdx.x - 8) * 2 + wc;
        const int mbase = row0 + wr * 64;
        const int b     = mbase >> 11;
        const int nt    = (mbase >> 6) & 31;
        __bf16* vt = Vf + ((size_t)(b * 8 + head) * 32 + nt) * 4096;
        #pragma unroll
        for (int ni = 0; ni < 4; ni++)
            #pragma unroll
            for (int kc = 0; kc < 2; kc++) {
                bf16x8 o = { (__bf16)acc[2*kc][ni][0],   (__bf16)acc[2*kc][ni][1],
                             (__bf16)acc[2*kc][ni][2],   (__bf16)acc[2*kc][ni][3],
                             (__bf16)acc[2*kc+1][ni][0], (__bf16)acc[2*kc+1][ni][1],
                             (__bf16)acc[2*kc+1][ni][2], (__bf16)acc[2*kc+1][ni][3] };
                *(bf16x8*)(vt + (ni * 2 + kc) * 512 + lane * 8) = o;
            }
        return;
    }

    // ---- Q/K blocks: stage C-tile (bf16) in LDS, then prep's RoPE verbatim.
    __syncthreads();                       // all waves done with As/Bs
    __bf16* Ct = smem;                     // 128 x 136 bf16 = 34 KB (stride pad)
    #pragma unroll
    for (int mi = 0; mi < 4; mi++)
        #pragma unroll
        for (int ni = 0; ni < 4; ni++)
            #pragma unroll
            for (int r = 0; r < 4; r++)
                Ct[(wr * 64 + mi * 16 + quad * 4 + r) * 136 + wc * 64 + ni * 16 + l16] =
                    (__bf16)acc[mi][ni][r];
    __syncthreads();

    const bool  isQ   = (blockIdx.x < 4);
    const float scale = isQ ? 0.18033688011112042f : 1.0f;   // 0.125*log2(e) for Q
    const int r  = t >> 2;                 // row within 64-row sub-tile
    const int d0 = (t & 3) << 4;           // dim start (16 dims per thread)
    const int b  = row0 >> 11;

    union Pack { __bf16 h[16]; uint4 u[2]; };
    #pragma unroll
    for (int u = 0; u < 4; u++) {          // 2 row-halves x 2 heads
        const int ntsub = u >> 1, hs = u & 1;
        const int nt  = ((row0 >> 6) & 31) + ntsub;
        const int pos = ((row0 + ntsub * 64) & 2047) + r;
        const int h   = (isQ ? blockIdx.x : blockIdx.x - 4) * 2 + hs;
        const int bh  = b * 8 + h;

        Pack vi, vo;
        const __bf16* lp = Ct + (size_t)(ntsub * 64 + r) * 136 + hs * 64 + d0;
        vi.u[0] = ((const uint4*)lp)[0];
        vi.u[1] = ((const uint4*)lp)[1];

        #pragma unroll
        for (int i = 0; i < 8; i++) {
            int p = (d0 >> 1) + i;
            float inv = exp2f(-0.41524101186092028f * (float)p);  // 10000^(-p/32)
            float ang = (float)pos * inv;
            float sn, cs;
            sincosf(ang, &sn, &cs);
            float e = (float)vi.h[2*i], o = (float)vi.h[2*i+1];
            vo.h[2*i]   = (__bf16)(scale * (e * cs - o * sn));
            vo.h[2*i+1] = (__bf16)(scale * (o * cs + e * sn));
        }

        if (isQ) {
            uint4* qd = (uint4*)(Qb + ((size_t)bh * N_SEQ + pos) * DH + d0);
            qd[0] = vo.u[0]; qd[1] = vo.u[1];
        } else {
            const int group = r >> 4, kl = r & 15;
            const int c = d0 >> 5, qd2 = (d0 & 31) >> 3;
            __bf16* kdst = Kf + ((size_t)bh * 32 + nt) * 4096
                              + (group * 2 + c) * 512 + (qd2 * 16 + kl) * 8;
            *(uint4*)kdst         = vo.u[0];
            *(uint4*)(kdst + 128) = vo.u[1];   // qd2+1
        }
    }
}

// ---------------- out-projection GEMM, 64x128 tile, 3-deep pipeline (R9).
__global__ __launch_bounds__(256) void gemm_out_kernel(const __bf16* __restrict__ A,
                                                       const __bf16* __restrict__ Bt,
                                                       float* __restrict__ C) {
    __shared__ __bf16 As[3][64 * 32];    // 12 KB
    __shared__ __bf16 Bs[3][128 * 32];   // 24 KB  (36 KB total)
    const int t = threadIdx.x;
    const int lane = t & 63;
    const int w = t >> 6;
    const int l16 = lane & 15, quad = lane >> 4;
    const int wr = w >> 1, wc = w & 1;   // wave tile: 32 rows x 64 cols
    const int row0 = blockIdx.y * 64, col0 = blockIdx.x * 128;

    f32x4 acc[2][4] = {};

    const int r0a = t >> 2, ks0 = (t & 3) * 8;
    const int r1a = (t + 256) >> 2;

    auto dma = [&](int kidx, int bb) {
        const int kt = kidx * 32;
        GLOAD_LDS16(A  + (size_t)(row0 + r0a) * DIM + kt + ks0, As[bb] + t * 8);
        GLOAD_LDS16(Bt + (size_t)(col0 + r0a) * DIM + kt + ks0, Bs[bb] + t * 8);
        GLOAD_LDS16(Bt + (size_t)(col0 + r1a) * DIM + kt + ks0, Bs[bb] + (t + 256) * 8);
    };

    dma(0, 0);
    dma(1, 1);
    int cb = 0, wb = 2;
    for (int i = 0; i < 16; i++) {
        SBAR();                              // A: all waves done computing step i-1
        if (i + 2 < 16) {
            dma(i + 2, wb);
            asm volatile("s_waitcnt vmcnt(6)" ::: "memory");   // oldest (step i) done
        } else if (i + 1 < 16) {
            asm volatile("s_waitcnt vmcnt(3)" ::: "memory");
        } else {
            asm volatile("s_waitcnt vmcnt(0)" ::: "memory");
        }
        SBAR();                              // B: publish step i

        bf16x8 af[2], bfr[4];
        #pragma unroll
        for (int mi = 0; mi < 2; mi++)
            af[mi] = *(const bf16x8*)(As[cb] + (wr * 32 + mi * 16 + l16) * 32 + quad * 8);
        #pragma unroll
        for (int ni = 0; ni < 4; ni++)
            bfr[ni] = *(const bf16x8*)(Bs[cb] + (wc * 64 + ni * 16 + l16) * 32 + quad * 8);
        __builtin_amdgcn_s_setprio(1);
        #pragma unroll
        for (int mi = 0; mi < 2; mi++)
            #pragma unroll
            for (int ni = 0; ni < 4; ni++)
                acc[mi][ni] = MFMA_BF16(af[mi], bfr[ni], acc[mi][ni], 0, 0, 0);
        __builtin_amdgcn_s_setprio(0);
        cb = (cb == 2) ? 0 : cb + 1;
        wb = (wb == 2) ? 0 : wb + 1;
    }
    #pragma unroll
    for (int mi = 0; mi < 2; mi++)
        #pragma unroll
        for (int ni = 0; ni < 4; ni++)
            #pragma unroll
            for (int r = 0; r < 4; r++) {
                int m = row0 + wr * 32 + mi * 16 + quad * 4 + r;
                int n = col0 + wc * 64 + ni * 16 + l16;
                C[(size_t)m * 512 + n] = acc[mi][ni][r];
            }
}

// ---------------- MFMA flash attention (R4 structure, best measured ~42.8 us).
__global__ __launch_bounds__(256, 2) void attn_mfma_kernel(const __bf16* __restrict__ Qb,
                                                           const __bf16* __restrict__ Kf,
                                                           const __bf16* __restrict__ Vf,
                                                           __bf16* __restrict__ attn) {
    __shared__ __bf16 kv[2][2][8192];    // [parity][pingpong][K(4096)|V(4096)] = 64 KB

    const int t    = threadIdx.x;
    const int w    = t >> 6;
    const int lane = t & 63;
    const int l16  = lane & 15;
    const int quad = lane >> 4;
    const int qh   = w >> 1;       // query half (0: q0..63, 1: q64..127)
    const int kp   = w & 1;        // key parity (tiles 2i+kp)

    const int bx = blockIdx.x;     // qc*32 + bh
    const int bh = bx & 31;
    const int qc = bx >> 5;        // 0..15 (128 queries each)
    const int b  = bh >> 3;
    const int h  = bh & 7;

    const int qrow0 = qc * 128 + qh * 64;
    const __bf16* Qh = Qb + ((size_t)bh * N_SEQ + qrow0) * DH;
    const __bf16* Kt = Kf + (size_t)bh * 32 * 4096;
    const __bf16* Vt = Vf + (size_t)bh * 32 * 4096;

    bf16x8 qa[4][2];
    #pragma unroll
    for (int f = 0; f < 4; f++) {
        qa[f][0] = *(const bf16x8*)(Qh + (size_t)(f * 16 + l16) * DH + quad * 8);
        qa[f][1] = *(const bf16x8*)(Qh + (size_t)(f * 16 + l16) * DH + 32 + quad * 8);
    }

    bf16x8 ones;
    #pragma unroll
    for (int i = 0; i < 8; i++) ones[i] = (__bf16)1.0f;

    f32x4 O[4][4] = {};
    f32x4 L[4] = {};

    auto dma_tile = [&](int tidx, int p, int pp) {   // tidx = 64-key tile (0..31)
        const __bf16* kss = Kt + (size_t)tidx * 4096;
        const __bf16* vss = Vt + (size_t)tidx * 4096;
        __bf16* dst = &kv[p][pp][0];
        GLOAD_LDS16(kss + t * 8,        dst + t * 8);
        GLOAD_LDS16(kss + 2048 + t * 8, dst + 2048 + t * 8);
        GLOAD_LDS16(vss + t * 8,        dst + 4096 + t * 8);
        GLOAD_LDS16(vss + 2048 + t * 8, dst + 4096 + 2048 + t * 8);
    };

    dma_tile(0, 0, 0);
    dma_tile(1, 1, 0);
    for (int i = 0; i < 16; i++) {           // 16 tile-pairs
        const int cur = i & 1;
        SBAR();                              // A: all waves done reading pp[cur^1]
        if (i + 1 < 16) {
            dma_tile(2 * (i + 1),     0, cur ^ 1);   // prefetch next pair
            dma_tile(2 * (i + 1) + 1, 1, cur ^ 1);   // (8 loads stay in flight)
            asm volatile("s_waitcnt vmcnt(8)" ::: "memory");  // pair i (mine) done
        } else {
            asm volatile("s_waitcnt vmcnt(0)" ::: "memory");
        }
        SBAR();                              // B: publish pair i to all waves

        const __bf16* kb = &kv[kp][cur][0];
        const __bf16* vb = &kv[kp][cur][4096];

        bf16x8 kf[4][2];
        #pragma unroll
        for (int g = 0; g < 4; g++)
            #pragma unroll
            for (int c = 0; c < 2; c++)
                kf[g][c] = *(const bf16x8*)(kb + (g * 2 + c) * 512 + lane * 8);

        bf16x8 pa[4][2];
        #pragma unroll
        for (int f = 0; f < 4; f++) {
            f32x4 S[4];
            __builtin_amdgcn_s_setprio(1);
            #pragma unroll
            for (int g = 0; g < 4; g++) {
                f32x4 z = {0, 0, 0, 0};
                z = MFMA_BF16(kf[g][0], qa[f][0], z, 0, 0, 0);
                z = MFMA_BF16(kf[g][1], qa[f][1], z, 0, 0, 0);
                S[g] = z;
            }
            __builtin_amdgcn_s_setprio(0);
            // lane l16 = query; S[g][r] = P(query=l16, key=g*16+4*quad+r)
            #pragma unroll
            for (int j = 0; j < 8; j++) {
                pa[f][0][j] = (__bf16)__builtin_amdgcn_exp2f(S[(j >> 2)][j & 3]);
                pa[f][1][j] = (__bf16)__builtin_amdgcn_exp2f(S[2 + (j >> 2)][j & 3]);
            }
        }

        bf16x8 vf[4][2];
        #pragma unroll
        for (int n = 0; n < 4; n++)
            #pragma unroll
            for (int kc = 0; kc < 2; kc++)
                vf[n][kc] = *(const bf16x8*)(vb + (n * 2 + kc) * 512 + lane * 8);

        __builtin_amdgcn_s_setprio(1);
        #pragma unroll
        for (int f = 0; f < 4; f++) {
            #pragma unroll
            for (int n = 0; n < 4; n++) {
                O[f][n] = MFMA_BF16(pa[f][0], vf[n][0], O[f][n], 0, 0, 0);
                O[f][n] = MFMA_BF16(pa[f][1], vf[n][1], O[f][n], 0, 0, 0);
            }
            L[f] = MFMA_BF16(pa[f][0], ones, L[f], 0, 0, 0);
            L[f] = MFMA_BF16(pa[f][1], ones, L[f], 0, 0, 0);
        }
        __builtin_amdgcn_s_setprio(0);
    }

    // ---- cross-parity reduction (padded strides 68/20 f32, no bank conflicts)
    __syncthreads();
    float* reds = (float*)&kv[0][0][0];
    float* myO = reds + (size_t)(qh * 64 + lane) * 68;
    float* myL = reds + 128 * 68 + (size_t)(qh * 64 + lane) * 20;
    if (kp == 1) {
        #pragma unroll
        for (int f = 0; f < 4; f++) {
            #pragma unroll
            for (int n = 0; n < 4; n++)
                *(f32x4*)(myO + (f * 4 + n) * 4) = O[f][n];
            *(f32x4*)(myL + f * 4) = L[f];
        }
    }
    __syncthreads();
    if (kp == 0) {
        #pragma unroll
        for (int f = 0; f < 4; f++) {
            #pragma unroll
            for (int n = 0; n < 4; n++)
                O[f][n] += *(const f32x4*)(myO + (f * 4 + n) * 4);
            L[f] += *(const f32x4*)(myL + f * 4);
        }
        #pragma unroll
        for (int f = 0; f < 4; f++) {
            float inv[4];
            #pragma unroll
            for (int r = 0; r < 4; r++) inv[r] = 1.0f / L[f][r];
            #pragma unroll
            for (int n = 0; n < 4; n++)
                #pragma unroll
                for (int r = 0; r < 4; r++) {
                    size_t row = (size_t)(b * N_SEQ + qrow0 + f * 16 + quad * 4 + r);
                    attn[row * 512 + h * DH + n * 16 + l16] =
                        (__bf16)(O[f][n][r] * inv[r]);
                }
        }
    }
}

extern "C" void kernel_launch(void* const* d_in, const int* in_sizes, int n_in,
                              void* d_out, int out_size, void* d_ws, size_t ws_size,
                              hipStream_t stream) {
    const float* x     = (const float*)d_in[0];
    const float* gamma = (const float*)d_in[1];
    const float* w_qkv = (const float*)d_in[2];
    const float* w_out = (const float*)d_in[3];
    float* out = (float*)d_out;

    // workspace (bf16): Abf 8.4MB | Wqkvt 1.5 | Woutt 0.5 | attnb 8.4 (in old
    // qkvb slot) | Qb,Kf,Vf 8.4 each.  qkvb itself is no longer materialized.
    __bf16* Abf   = (__bf16*)d_ws;
    __bf16* Wqkvt = Abf + (size_t)ROWS * DIM;
    __bf16* Woutt = Wqkvt + (size_t)QKV_N * DIM;
    __bf16* attnb = Woutt + (size_t)DIM * DIM;
    __bf16* Qb    = attnb + (size_t)ROWS * QKV_N;
    __bf16* Kf    = Qb + (size_t)NH * B_SZ * N_SEQ * DH;
    __bf16* Vf    = Kf + (size_t)NH * B_SZ * N_SEQ * DH;

    prelude_kernel<<<2304, 256, 0, stream>>>(x, gamma, w_qkv, w_out,
                                             Abf, Wqkvt, Woutt);
    gemm_qkv_kernel<<<dim3(QKV_N / 128, ROWS / 128), 256, 0, stream>>>(
        Abf, Wqkvt, Qb, Kf, Vf);
    attn_mfma_kernel<<<512, 256, 0, stream>>>(Qb, Kf, Vf, attnb);
    gemm_out_kernel<<<dim3(4, 128), 256, 0, stream>>>(attnb, Woutt, out);
}